// Round 1
// baseline (976.465 us; speedup 1.0000x reference)
//
#include <hip/hip_runtime.h>

typedef unsigned short u16;
typedef short vbf16x8 __attribute__((ext_vector_type(8)));   // 8 bf16 as shorts (4 VGPR)
typedef float vf32x4 __attribute__((ext_vector_type(4)));
typedef int vi32x4 __attribute__((ext_vector_type(4)));

#define MFMA16(a,b,c) __builtin_amdgcn_mfma_f32_16x16x32_bf16((a),(b),(c),0,0,0)

__device__ __forceinline__ u16 f2bf(float f) {
  union { float f; unsigned u; } c; c.f = f;
  unsigned r = c.u + 0x7fffu + ((c.u >> 16) & 1u);
  return (u16)(r >> 16);
}

// ---------------- prep: weight transposes (bf16) ----------------
// wcatT[n][k], n in [0,384): n<128 -> w1[128+k][n] (U part), n<256 -> w1[k][n-128] (T part),
// else uw1[k][n-256] (V part).  w2T[n][k]=w2[k][n]; u1bT[n][k]=uw1[128+k][n]; u2T[n][k]=uw2[k][n].
__global__ __launch_bounds__(256) void k_prep_w(
    const float* __restrict__ w1, const float* __restrict__ w2,
    const float* __restrict__ u1, const float* __restrict__ u2,
    u16* __restrict__ wcatT, u16* __restrict__ w2T,
    u16* __restrict__ u1bT, u16* __restrict__ u2T) {
  int id = blockIdx.x * 256 + threadIdx.x;
  if (id < 49152) {
    int n = id >> 7, k = id & 127;
    float v;
    if (n < 128) v = w1[(128 + k) * 128 + n];
    else if (n < 256) v = w1[k * 128 + (n - 128)];
    else v = u1[k * 128 + (n - 256)];
    wcatT[id] = f2bf(v);
  } else {
    int id2 = id - 49152;
    int m = id2 >> 14, r = id2 & 16383;
    int n = r >> 7, k = r & 127;
    if (m == 0) w2T[r] = f2bf(w2[k * 128 + n]);
    else if (m == 1) u1bT[r] = f2bf(u1[(128 + k) * 128 + n]);
    else u2T[r] = f2bf(u2[k * 128 + n]);
  }
}

// ---------------- norms: xn (f32 + bf16), x (bf16) ----------------
__global__ __launch_bounds__(256) void k_norm(
    const float* __restrict__ x, float* __restrict__ xnf,
    u16* __restrict__ xnbf, u16* __restrict__ xbf) {
  int lane = threadIdx.x & 63, w = threadIdx.x >> 6;
  int row = blockIdx.x * 4 + w;
  size_t b = (size_t)row * 128;
  float v0 = x[b + lane], v1 = x[b + 64 + lane];
  float ss = v0 * v0 + v1 * v1;
  #pragma unroll
  for (int m = 32; m > 0; m >>= 1) ss += __shfl_xor(ss, m);
  float d = fmaxf(sqrtf(ss), 1e-8f);
  float n0 = v0 / d, n1 = v1 / d;
  xnf[b + lane] = n0; xnf[b + 64 + lane] = n1;
  xnbf[b + lane] = f2bf(n0); xnbf[b + 64 + lane] = f2bf(n1);
  xbf[b + lane] = f2bf(v0); xbf[b + 64 + lane] = f2bf(v1);
}

// ---------------- streaming sim + top-22-per-segment candidates ----------------
// Block: 64 rows (4 waves, 1 rowtile of 16 rows per wave), iterates 256 col-tiles of 32
// over its half of the columns (blockIdx.x&1). Per thread: private top-22 list over its
// (row, seg) stream (seg = 8 cols of each 32-col tile -> 2048-element stream).
__global__ __launch_bounds__(256) void k_sim_topk(
    const u16* __restrict__ xnbf, float* __restrict__ candV, int* __restrict__ candI) {
  __shared__ u16  Bpan[32 * 136];     // 32 col-rows of xn, padded stride 272B
  __shared__ float sim[64 * 33];      // sim tile [64 rows][32 cols], pad 33
  __shared__ float cval[256 * 22];    // per-thread candidate values
  __shared__ u16   cidx[256 * 22];    // per-thread candidate cols

  const int tid = threadIdx.x;
  const int lane = tid & 63, w = tid >> 6;
  const int lr = lane & 15, lg = lane >> 4;
  const int rb = blockIdx.x >> 1, half = blockIdx.x & 1;
  const int rowbase = rb * 64;

  // A fragments in registers: wave w owns rows rowbase + w*16 .. +16, all 4 k-steps
  vbf16x8 af[4];
  {
    const u16* rp = xnbf + (size_t)(rowbase + w * 16 + lr) * 128;
    #pragma unroll
    for (int ks = 0; ks < 4; ++ks)
      af[ks] = *(const vbf16x8*)(rp + ks * 32 + lg * 8);
  }

  const int lb = tid * 22;
  #pragma unroll
  for (int s = 0; s < 22; ++s) cval[lb + s] = -1e30f;
  float curmin = -1e30f; int minslot = 0;
  const int srow = tid >> 2, seg = tid & 3;

  #pragma unroll 1
  for (int it = 0; it < 256; ++it) {
    const int colbase = (half * 256 + it) * 32;
    { // stage B panel: 32 rows x 256B = 8KB
      const vi32x4* src = (const vi32x4*)(xnbf + (size_t)colbase * 128);
      #pragma unroll
      for (int j2 = 0; j2 < 2; ++j2) {
        int e16 = tid + j2 * 256;
        vi32x4 d = src[e16];
        int row = e16 >> 4, off = e16 & 15;
        *(vi32x4*)(&Bpan[row * 136 + off * 8]) = d;
      }
    }
    __syncthreads();
    // MFMA: rowtile w x coltiles {0,1}
    vf32x4 acc0 = {0.f, 0.f, 0.f, 0.f}, acc1 = {0.f, 0.f, 0.f, 0.f};
    #pragma unroll
    for (int ks = 0; ks < 4; ++ks) {
      vbf16x8 b0 = *(const vbf16x8*)(&Bpan[lr * 136 + ks * 32 + lg * 8]);
      vbf16x8 b1 = *(const vbf16x8*)(&Bpan[(16 + lr) * 136 + ks * 32 + lg * 8]);
      acc0 = MFMA16(af[ks], b0, acc0);
      acc1 = MFMA16(af[ks], b1, acc1);
    }
    { // write sim tile: D layout col=lane&15, row=(lane>>4)*4+reg
      int row0 = w * 16 + lg * 4;
      #pragma unroll
      for (int r = 0; r < 4; ++r) sim[(row0 + r) * 33 + lr] = acc0[r];
      #pragma unroll
      for (int r = 0; r < 4; ++r) sim[(row0 + r) * 33 + 16 + lr] = acc1[r];
    }
    __syncthreads();
    { // scan: row srow, cols seg*8..+8
      const float* sp = &sim[srow * 33 + seg * 8];
      #pragma unroll
      for (int i = 0; i < 8; ++i) {
        float v = sp[i];
        if (v > curmin) {
          cval[lb + minslot] = v;
          cidx[lb + minslot] = (u16)(colbase + seg * 8 + i);
          curmin = cval[lb]; minslot = 0;
          #pragma unroll
          for (int s = 1; s < 22; ++s) {
            float c = cval[lb + s];
            if (c < curmin) { curmin = c; minslot = s; }
          }
        }
      }
    }
    __syncthreads();
  }
  { // dump candidates: 176 per row = 2 halves x 4 segs x 22
    int grow = rowbase + srow;
    float* dv = candV + (size_t)grow * 176 + half * 88 + seg * 22;
    int*   di = candI + (size_t)grow * 176 + half * 88 + seg * 22;
    #pragma unroll
    for (int s = 0; s < 22; ++s) { dv[s] = cval[lb + s]; di[s] = (int)cidx[lb + s]; }
  }
}

// ---------------- merge 176 cands -> mfma-top-28 -> fp32 rescore -> top-20 ----------------
__global__ __launch_bounds__(256) void k_select(
    const float* __restrict__ xnf,
    const float* __restrict__ candV, const int* __restrict__ candI,
    float* __restrict__ topV, int* __restrict__ topI) {
  __shared__ float xrow[4][128];
  const int tid = threadIdx.x, lane = tid & 63, w = tid >> 6;
  const int i = blockIdx.x * 4 + w;
  xrow[w][lane] = xnf[(size_t)i * 128 + lane];
  xrow[w][64 + lane] = xnf[(size_t)i * 128 + 64 + lane];
  __syncthreads();

  float v[3]; int ix[3];
  const float* cv = candV + (size_t)i * 176;
  const int*   ci = candI + (size_t)i * 176;
  v[0] = cv[lane];        ix[0] = ci[lane];
  v[1] = cv[64 + lane];   ix[1] = ci[64 + lane];
  if (lane < 48) { v[2] = cv[128 + lane]; ix[2] = ci[128 + lane]; }
  else           { v[2] = -1e30f;         ix[2] = 0x7fffffff; }

  // phase 1: top-28 by mfma value (margin 8 over K=20 makes selection exact after rescore)
  int keepI = 0x7fffffff;
  for (int t = 0; t < 28; ++t) {
    float bv = v[0]; int bi = ix[0]; int bs = 0;
    if (v[1] > bv || (v[1] == bv && ix[1] < bi)) { bv = v[1]; bi = ix[1]; bs = 1; }
    if (v[2] > bv || (v[2] == bv && ix[2] < bi)) { bv = v[2]; bi = ix[2]; bs = 2; }
    int bl = (lane << 2) | bs;
    #pragma unroll
    for (int m = 1; m < 64; m <<= 1) {
      float ov = __shfl_xor(bv, m); int oi = __shfl_xor(bi, m); int ol = __shfl_xor(bl, m);
      if (ov > bv || (ov == bv && oi < bi)) { bv = ov; bi = oi; bl = ol; }
    }
    if ((bl >> 2) == lane) v[bl & 3] = -1e30f;
    if (t == lane) keepI = bi;
  }
  // phase 2: exact fp32 rescore on lanes 0..27
  float rv = -1e30f;
  if (lane < 28) {
    const float* xj = xnf + (size_t)keepI * 128;
    float s = 0.f;
    for (int k4 = 0; k4 < 32; ++k4) {
      vf32x4 a = *(const vf32x4*)&xrow[w][k4 * 4];
      vf32x4 b = *(const vf32x4*)&xj[k4 * 4];
      s += a[0] * b[0] + a[1] * b[1] + a[2] * b[2] + a[3] * b[3];
    }
    rv = s;
  }
  int rix = (lane < 28) ? keepI : 0x7fffffff;
  // phase 3: top-20 by rescored value (tie -> lower index, matching np)
  for (int t = 0; t < 20; ++t) {
    float bv = rv; int bi = rix; int bl = lane;
    #pragma unroll
    for (int m = 1; m < 64; m <<= 1) {
      float ov = __shfl_xor(bv, m); int oi = __shfl_xor(bi, m); int ol = __shfl_xor(bl, m);
      if (ov > bv || (ov == bv && oi < bi)) { bv = ov; bi = oi; bl = ol; }
    }
    if (lane == 0) { topV[(size_t)i * 20 + t] = bv; topI[(size_t)i * 20 + t] = bi; }
    if (bl == lane) rv = -1e30f;
  }
}

// ---------------- precompute U = x@w1[128:], T = x@w1[:128], V = x@uw1[:128] ----------------
__global__ __launch_bounds__(256) void k_pre(
    const u16* __restrict__ xbf, const u16* __restrict__ wcatT,
    float* __restrict__ U, float* __restrict__ T, float* __restrict__ V) {
  const int tid = threadIdx.x, lane = tid & 63, w = tid >> 6;
  const int lr = lane & 15, lg = lane >> 4;
  const int rowbase = blockIdx.x * 64, cb = blockIdx.y;
  const int a = w >> 1, b = w & 1;
  vbf16x8 af[2][4];
  #pragma unroll
  for (int ar = 0; ar < 2; ++ar) {
    const u16* rp = xbf + (size_t)(rowbase + (a * 2 + ar) * 16 + lr) * 128;
    #pragma unroll
    for (int ks = 0; ks < 4; ++ks) af[ar][ks] = *(const vbf16x8*)(rp + ks * 32 + lg * 8);
  }
  vf32x4 z = {0.f, 0.f, 0.f, 0.f};
  vf32x4 acc[2][2] = {{z, z}, {z, z}};
  #pragma unroll
  for (int ks = 0; ks < 4; ++ks) {
    vbf16x8 bf[2];
    #pragma unroll
    for (int cbl = 0; cbl < 2; ++cbl) {
      int gcol = cb * 64 + (b * 2 + cbl) * 16 + lr;
      bf[cbl] = *(const vbf16x8*)(wcatT + (size_t)gcol * 128 + ks * 32 + lg * 8);
    }
    #pragma unroll
    for (int ar = 0; ar < 2; ++ar)
      #pragma unroll
      for (int cbl = 0; cbl < 2; ++cbl)
        acc[ar][cbl] = MFMA16(af[ar][ks], bf[cbl], acc[ar][cbl]);
  }
  #pragma unroll
  for (int ar = 0; ar < 2; ++ar)
    #pragma unroll
    for (int cbl = 0; cbl < 2; ++cbl) {
      int gcol = cb * 64 + (b * 2 + cbl) * 16 + lr;
      #pragma unroll
      for (int r = 0; r < 4; ++r) {
        int grow = rowbase + (a * 2 + ar) * 16 + lg * 4 + r;
        float vv = acc[ar][cbl][r];
        if (gcol < 128)      U[(size_t)grow * 128 + gcol] = vv;
        else if (gcol < 256) T[(size_t)grow * 128 + (gcol - 128)] = vv;
        else                 V[(size_t)grow * 128 + (gcol - 256)] = vv;
      }
    }
}

// ---------------- fused: softmax, G = sum_e s_e*relu(T_i+U_j+b1), h_agg, update MLP ----------------
__global__ __launch_bounds__(256) void k_msg_upd(
    const float* __restrict__ x,
    const float* __restrict__ Uarr, const float* __restrict__ Tarr, const float* __restrict__ Varr,
    const float* __restrict__ topV, const int* __restrict__ topI,
    const float* __restrict__ b1, const float* __restrict__ b2,
    const float* __restrict__ ub1, const float* __restrict__ ub2,
    const u16* __restrict__ w2T, const u16* __restrict__ u1bT, const u16* __restrict__ u2T,
    float* __restrict__ out) {
  __shared__ float wsm[32 * 20];
  __shared__ int   ism[32 * 20];
  __shared__ u16   Gbf[32 * 136];
  __shared__ u16   Hbf[32 * 136];
  const int tid = threadIdx.x, lane = tid & 63, w = tid >> 6;
  const int lr = lane & 15, lg = lane >> 4;
  const int base = blockIdx.x * 32;

  if (tid < 32) { // softmax over rescored top-20 sims
    int i = base + tid;
    float vv[20]; float mx = -1e30f;
    #pragma unroll
    for (int e = 0; e < 20; ++e) { vv[e] = topV[(size_t)i * 20 + e]; mx = fmaxf(mx, vv[e]); }
    float s = 0.f;
    #pragma unroll
    for (int e = 0; e < 20; ++e) { vv[e] = __expf(vv[e] - mx); s += vv[e]; }
    float inv = 1.f / s;
    #pragma unroll
    for (int e = 0; e < 20; ++e) {
      wsm[tid * 20 + e] = vv[e] * inv;
      ism[tid * 20 + e] = topI[(size_t)i * 20 + e];
    }
  }
  __syncthreads();

  { // G step: 8 threads per row, 16 channels each
    int r = tid >> 3, q = tid & 7, ch0 = q * 16;
    int i = base + r;
    vf32x4 z = {0.f, 0.f, 0.f, 0.f};
    vf32x4 tr[4], br[4], acc[4];
    #pragma unroll
    for (int c = 0; c < 4; ++c) {
      tr[c] = *(const vf32x4*)&Tarr[(size_t)i * 128 + ch0 + c * 4];
      br[c] = *(const vf32x4*)&b1[ch0 + c * 4];
      acc[c] = z;
    }
    #pragma unroll 1
    for (int e = 0; e < 20; ++e) {
      int j = ism[r * 20 + e]; float s = wsm[r * 20 + e];
      const vf32x4* up = (const vf32x4*)&Uarr[(size_t)j * 128 + ch0];
      #pragma unroll
      for (int c = 0; c < 4; ++c) {
        vf32x4 u = up[c];
        #pragma unroll
        for (int zz = 0; zz < 4; ++zz) {
          float p = tr[c][zz] + u[zz] + br[c][zz];
          acc[c][zz] += s * fmaxf(p, 0.f);
        }
      }
    }
    #pragma unroll
    for (int c = 0; c < 4; ++c)
      #pragma unroll
      for (int zz = 0; zz < 4; ++zz)
        Gbf[r * 136 + ch0 + c * 4 + zz] = f2bf(acc[c][zz]);
  }
  __syncthreads();

  const int rt = w >> 1, cg = w & 1;
  vf32x4 z4 = {0.f, 0.f, 0.f, 0.f};
  { // GEMM1: h_agg = G @ w2 + b2 -> Hbf
    vf32x4 acc[4] = {z4, z4, z4, z4};
    #pragma unroll
    for (int ks = 0; ks < 4; ++ks) {
      vbf16x8 a = *(const vbf16x8*)&Gbf[(rt * 16 + lr) * 136 + ks * 32 + lg * 8];
      #pragma unroll
      for (int c = 0; c < 4; ++c) {
        int col = (cg * 4 + c) * 16 + lr;
        vbf16x8 bb = *(const vbf16x8*)(w2T + (size_t)col * 128 + ks * 32 + lg * 8);
        acc[c] = MFMA16(a, bb, acc[c]);
      }
    }
    #pragma unroll
    for (int c = 0; c < 4; ++c) {
      int col = (cg * 4 + c) * 16 + lr;
      float bias = b2[col];
      #pragma unroll
      for (int r = 0; r < 4; ++r) {
        int row = rt * 16 + lg * 4 + r;
        Hbf[row * 136 + col] = f2bf(acc[c][r] + bias);
      }
    }
  }
  __syncthreads();
  { // GEMM2: pre = h_agg @ uw1[128:] + V_i + ub1, relu -> Gbf (reused as P)
    vf32x4 acc[4] = {z4, z4, z4, z4};
    #pragma unroll
    for (int ks = 0; ks < 4; ++ks) {
      vbf16x8 a = *(const vbf16x8*)&Hbf[(rt * 16 + lr) * 136 + ks * 32 + lg * 8];
      #pragma unroll
      for (int c = 0; c < 4; ++c) {
        int col = (cg * 4 + c) * 16 + lr;
        vbf16x8 bb = *(const vbf16x8*)(u1bT + (size_t)col * 128 + ks * 32 + lg * 8);
        acc[c] = MFMA16(a, bb, acc[c]);
      }
    }
    #pragma unroll
    for (int c = 0; c < 4; ++c) {
      int col = (cg * 4 + c) * 16 + lr;
      float bias = ub1[col];
      #pragma unroll
      for (int r = 0; r < 4; ++r) {
        int row = rt * 16 + lg * 4 + r;
        float vv = acc[c][r] + Varr[(size_t)(base + row) * 128 + col] + bias;
        Gbf[row * 136 + col] = f2bf(fmaxf(vv, 0.f));
      }
    }
  }
  __syncthreads();
  { // GEMM3: out = x + P @ uw2 + ub2
    vf32x4 acc[4] = {z4, z4, z4, z4};
    #pragma unroll
    for (int ks = 0; ks < 4; ++ks) {
      vbf16x8 a = *(const vbf16x8*)&Gbf[(rt * 16 + lr) * 136 + ks * 32 + lg * 8];
      #pragma unroll
      for (int c = 0; c < 4; ++c) {
        int col = (cg * 4 + c) * 16 + lr;
        vbf16x8 bb = *(const vbf16x8*)(u2T + (size_t)col * 128 + ks * 32 + lg * 8);
        acc[c] = MFMA16(a, bb, acc[c]);
      }
    }
    #pragma unroll
    for (int c = 0; c < 4; ++c) {
      int col = (cg * 4 + c) * 16 + lr;
      float bias = ub2[col];
      #pragma unroll
      for (int r = 0; r < 4; ++r) {
        int row = rt * 16 + lg * 4 + r;
        size_t o = (size_t)(base + row) * 128 + col;
        out[o] = x[o] + acc[c][r] + bias;
      }
    }
  }
}

extern "C" void kernel_launch(void* const* d_in, const int* in_sizes, int n_in,
                              void* d_out, int out_size, void* d_ws, size_t ws_size,
                              hipStream_t stream) {
  (void)in_sizes; (void)n_in; (void)out_size; (void)ws_size;
  const float* x   = (const float*)d_in[0];
  const float* w1  = (const float*)d_in[1];
  const float* b1  = (const float*)d_in[2];
  const float* w2  = (const float*)d_in[3];
  const float* b2  = (const float*)d_in[4];
  const float* uw1 = (const float*)d_in[5];
  const float* ub1 = (const float*)d_in[6];
  const float* uw2 = (const float*)d_in[7];
  const float* ub2 = (const float*)d_in[8];
  float* out = (float*)d_out;
  char* ws = (char*)d_ws;

  u16*   xnbf  = (u16*)(ws + 0);                         // 4 MB
  u16*   xbf   = (u16*)(ws + (4u << 20));                // 4 MB
  float* xnf   = (float*)(ws + (8u << 20));              // 8 MB
  u16*   wcatT = (u16*)(ws + (16u << 20));               // 96 KB
  u16*   w2T   = (u16*)(ws + (16u << 20) + 131072);      // 32 KB
  u16*   u1bT  = (u16*)(ws + (16u << 20) + 163840);      // 32 KB
  u16*   u2T   = (u16*)(ws + (16u << 20) + 196608);      // 32 KB
  float* candV = (float*)(ws + (17u << 20));             // 11.5 MB
  int*   candI = (int*)(ws + (29u << 20));               // 11.5 MB
  float* topV  = (float*)(ws + (41u << 20));             // 1.31 MB
  int*   topI  = (int*)(ws + (43u << 20));               // 1.31 MB
  float* Uarr  = (float*)(ws + (45u << 20));             // 8 MB
  float* Tarr  = (float*)(ws + (53u << 20));             // 8 MB
  float* Varr  = (float*)(ws + (61u << 20));             // 8 MB -> total 69 MB

  hipLaunchKernelGGL(k_prep_w, dim3(384), dim3(256), 0, stream,
                     w1, w2, uw1, uw2, wcatT, w2T, u1bT, u2T);
  hipLaunchKernelGGL(k_norm, dim3(4096), dim3(256), 0, stream, x, xnf, xnbf, xbf);
  hipLaunchKernelGGL(k_sim_topk, dim3(512), dim3(256), 0, stream, xnbf, candV, candI);
  hipLaunchKernelGGL(k_select, dim3(4096), dim3(256), 0, stream, xnf, candV, candI, topV, topI);
  hipLaunchKernelGGL(k_pre, dim3(256, 6), dim3(256), 0, stream, xbf, wcatT, Uarr, Tarr, Varr);
  hipLaunchKernelGGL(k_msg_upd, dim3(512), dim3(256), 0, stream,
                     x, Uarr, Tarr, Varr, topV, topI, b1, b2, ub1, ub2, w2T, u1bT, u2T, out);
}

// Round 2
// 760.343 us; speedup vs baseline: 1.2842x; 1.2842x over previous
//
#include <hip/hip_runtime.h>

typedef unsigned short u16;
typedef short vbf16x8 __attribute__((ext_vector_type(8)));   // 8 bf16 as shorts (4 VGPR)
typedef float vf32x4 __attribute__((ext_vector_type(4)));
typedef int vi32x4 __attribute__((ext_vector_type(4)));

#define MFMA16(a,b,c) __builtin_amdgcn_mfma_f32_16x16x32_bf16((a),(b),(c),0,0,0)

__device__ __forceinline__ u16 f2bf(float f) {
  union { float f; unsigned u; } c; c.f = f;
  unsigned r = c.u + 0x7fffu + ((c.u >> 16) & 1u);
  return (u16)(r >> 16);
}

// ---------------- prep: weight transposes (bf16) ----------------
__global__ __launch_bounds__(256) void k_prep_w(
    const float* __restrict__ w1, const float* __restrict__ w2,
    const float* __restrict__ u1, const float* __restrict__ u2,
    u16* __restrict__ wcatT, u16* __restrict__ w2T,
    u16* __restrict__ u1bT, u16* __restrict__ u2T) {
  int id = blockIdx.x * 256 + threadIdx.x;
  if (id < 49152) {
    int n = id >> 7, k = id & 127;
    float v;
    if (n < 128) v = w1[(128 + k) * 128 + n];
    else if (n < 256) v = w1[k * 128 + (n - 128)];
    else v = u1[k * 128 + (n - 256)];
    wcatT[id] = f2bf(v);
  } else {
    int id2 = id - 49152;
    int m = id2 >> 14, r = id2 & 16383;
    int n = r >> 7, k = r & 127;
    if (m == 0) w2T[r] = f2bf(w2[k * 128 + n]);
    else if (m == 1) u1bT[r] = f2bf(u1[(128 + k) * 128 + n]);
    else u2T[r] = f2bf(u2[k * 128 + n]);
  }
}

// ---------------- norms: xn (f32 + bf16), x (bf16); zero cnt2 ----------------
__global__ __launch_bounds__(256) void k_norm(
    const float* __restrict__ x, float* __restrict__ xnf,
    u16* __restrict__ xnbf, u16* __restrict__ xbf, int* __restrict__ cnt2) {
  int gid = blockIdx.x * 256 + threadIdx.x;
  if (gid < 32768) cnt2[gid] = 0;
  int lane = threadIdx.x & 63, w = threadIdx.x >> 6;
  int row = blockIdx.x * 4 + w;
  size_t b = (size_t)row * 128;
  float v0 = x[b + lane], v1 = x[b + 64 + lane];
  float ss = v0 * v0 + v1 * v1;
  #pragma unroll
  for (int m = 32; m > 0; m >>= 1) ss += __shfl_xor(ss, m);
  float d = fmaxf(sqrtf(ss), 1e-8f);
  float n0 = v0 / d, n1 = v1 / d;
  xnf[b + lane] = n0; xnf[b + 64 + lane] = n1;
  xnbf[b + lane] = f2bf(n0); xnbf[b + 64 + lane] = f2bf(n1);
  xbf[b + lane] = f2bf(v0); xbf[b + 64 + lane] = f2bf(v1);
}

// ---------------- 2-pass sim: (1) per-row threshold via lane-top-3, (2) capture >= theta ----------------
// Block handles 64 rows x one half (8192 cols). Pass 1: register top-3 per (row,lane) stream ->
// theta = 20th largest of 48 values (guaranteed <= true MFMA-20th by subset order-stat).
// Pass 2: recompute identical MFMAs, append v >= theta to global per-(row,half) buffer (cap 96).
__global__ __launch_bounds__(256) void k_sim_topk(
    const u16* __restrict__ xnbf, float* __restrict__ candV, int* __restrict__ candI,
    int* __restrict__ cnt2) {
  __shared__ u16 Bpan[32 * 136];   // 32 col-rows of xn, padded stride 272B (2-way bank = free)

  const int tid = threadIdx.x;
  const int lane = tid & 63, w = tid >> 6;
  const int lr = lane & 15, lg = lane >> 4;
  // XCD swizzle: xcd = blockIdx%8; odd XCDs half 1; each XCD: 64 blocks, contiguous 64-rb range
  const int xd = blockIdx.x & 7, q = blockIdx.x >> 3;
  const int half = xd & 1;
  const int rb = (xd >> 1) * 64 + q;
  const int rowbase = rb * 64;

  // A fragments in registers
  vbf16x8 af[4];
  {
    const u16* rp = xnbf + (size_t)(rowbase + w * 16 + lr) * 128;
    #pragma unroll
    for (int ks = 0; ks < 4; ++ks) af[ks] = *(const vbf16x8*)(rp + ks * 32 + lg * 8);
  }

  const size_t tilebase = (size_t)half * 256;

  float m1[4], m2[4], m3[4];
  #pragma unroll
  for (int r = 0; r < 4; ++r) { m1[r] = -1e30f; m2[r] = -1e30f; m3[r] = -1e30f; }

  vi32x4 st0, st1;
  // ---------------- pass 1 ----------------
  { // prologue: tile 0
    const vi32x4* src = (const vi32x4*)(xnbf + (tilebase + 0) * 32 * 128);
    st0 = src[tid]; st1 = src[tid + 256];
    *(vi32x4*)&Bpan[(tid >> 4) * 136 + (tid & 15) * 8] = st0;
    int e1 = tid + 256;
    *(vi32x4*)&Bpan[(e1 >> 4) * 136 + (e1 & 15) * 8] = st1;
  }
  __syncthreads();
  #pragma unroll 1
  for (int it = 0; it < 256; ++it) {
    if (it < 255) { // issue next-tile loads (latency hidden under MFMA+top3)
      const vi32x4* src = (const vi32x4*)(xnbf + (tilebase + it + 1) * 32 * 128);
      st0 = src[tid]; st1 = src[tid + 256];
    }
    vf32x4 acc0 = {0.f,0.f,0.f,0.f}, acc1 = {0.f,0.f,0.f,0.f};
    #pragma unroll
    for (int ks = 0; ks < 4; ++ks) {
      vbf16x8 b0 = *(const vbf16x8*)(&Bpan[lr * 136 + ks * 32 + lg * 8]);
      vbf16x8 b1 = *(const vbf16x8*)(&Bpan[(16 + lr) * 136 + ks * 32 + lg * 8]);
      acc0 = MFMA16(af[ks], b0, acc0);
      acc1 = MFMA16(af[ks], b1, acc1);
    }
    #pragma unroll
    for (int r = 0; r < 4; ++r) { // branchless top-3 update, 2 values per row
      #pragma unroll
      for (int h = 0; h < 2; ++h) {
        float v = h ? acc1[r] : acc0[r];
        bool g1 = v > m1[r], g2 = v > m2[r], g3 = v > m3[r];
        m3[r] = g2 ? m2[r] : (g3 ? v : m3[r]);
        m2[r] = g1 ? m1[r] : (g2 ? v : m2[r]);
        m1[r] = g1 ? v : m1[r];
      }
    }
    __syncthreads();
    if (it < 255) {
      *(vi32x4*)&Bpan[(tid >> 4) * 136 + (tid & 15) * 8] = st0;
      int e1 = tid + 256;
      *(vi32x4*)&Bpan[(e1 >> 4) * 136 + (e1 & 15) * 8] = st1;
    }
    __syncthreads();
  }

  // theta per row: 20th-largest of the 16-lane x top-3 collection (shfl max-extract x20)
  float th[4];
  #pragma unroll
  for (int r = 0; r < 4; ++r) {
    float a0 = m1[r], a1 = m2[r], a2 = m3[r];
    float g = -1e30f;
    for (int t = 0; t < 20; ++t) {
      float loc = fmaxf(a0, fmaxf(a1, a2));
      g = loc;
      #pragma unroll
      for (int mm = 1; mm < 16; mm <<= 1) g = fmaxf(g, __shfl_xor(g, mm));
      a0 = (a0 == g) ? -1e30f : a0;
      a1 = (a1 == g) ? -1e30f : a1;
      a2 = (a2 == g) ? -1e30f : a2;
    }
    th[r] = g;
  }

  // ---------------- pass 2: identical MFMAs, capture v >= theta ----------------
  { // prologue: tile 0
    const vi32x4* src = (const vi32x4*)(xnbf + (tilebase + 0) * 32 * 128);
    st0 = src[tid]; st1 = src[tid + 256];
  }
  __syncthreads();
  {
    *(vi32x4*)&Bpan[(tid >> 4) * 136 + (tid & 15) * 8] = st0;
    int e1 = tid + 256;
    *(vi32x4*)&Bpan[(e1 >> 4) * 136 + (e1 & 15) * 8] = st1;
  }
  __syncthreads();
  #pragma unroll 1
  for (int it = 0; it < 256; ++it) {
    const int colbase = (half * 256 + it) * 32;
    if (it < 255) {
      const vi32x4* src = (const vi32x4*)(xnbf + (tilebase + it + 1) * 32 * 128);
      st0 = src[tid]; st1 = src[tid + 256];
    }
    vf32x4 acc0 = {0.f,0.f,0.f,0.f}, acc1 = {0.f,0.f,0.f,0.f};
    #pragma unroll
    for (int ks = 0; ks < 4; ++ks) {
      vbf16x8 b0 = *(const vbf16x8*)(&Bpan[lr * 136 + ks * 32 + lg * 8]);
      vbf16x8 b1 = *(const vbf16x8*)(&Bpan[(16 + lr) * 136 + ks * 32 + lg * 8]);
      acc0 = MFMA16(af[ks], b0, acc0);
      acc1 = MFMA16(af[ks], b1, acc1);
    }
    #pragma unroll
    for (int r = 0; r < 4; ++r) {
      const int grow = rowbase + w * 16 + lg * 4 + r;
      if (acc0[r] >= th[r]) {
        int s = atomicAdd(&cnt2[grow * 2 + half], 1);
        if (s < 96) {
          size_t o = (size_t)grow * 192 + half * 96 + s;
          candV[o] = acc0[r]; candI[o] = colbase + lr;
        }
      }
      if (acc1[r] >= th[r]) {
        int s = atomicAdd(&cnt2[grow * 2 + half], 1);
        if (s < 96) {
          size_t o = (size_t)grow * 192 + half * 96 + s;
          candV[o] = acc1[r]; candI[o] = colbase + 16 + lr;
        }
      }
    }
    __syncthreads();
    if (it < 255) {
      *(vi32x4*)&Bpan[(tid >> 4) * 136 + (tid & 15) * 8] = st0;
      int e1 = tid + 256;
      *(vi32x4*)&Bpan[(e1 >> 4) * 136 + (e1 & 15) * 8] = st1;
    }
    __syncthreads();
  }
}

// ---------------- merge candidates -> mfma-top-28 -> fp32 rescore -> top-20 ----------------
__global__ __launch_bounds__(256) void k_select(
    const float* __restrict__ xnf,
    const float* __restrict__ candV, const int* __restrict__ candI,
    const int* __restrict__ cnt2,
    float* __restrict__ topV, int* __restrict__ topI) {
  __shared__ float xrow[4][128];
  const int tid = threadIdx.x, lane = tid & 63, w = tid >> 6;
  const int i = blockIdx.x * 4 + w;
  xrow[w][lane] = xnf[(size_t)i * 128 + lane];
  xrow[w][64 + lane] = xnf[(size_t)i * 128 + 64 + lane];
  __syncthreads();

  int c0 = cnt2[i * 2], c1 = cnt2[i * 2 + 1];
  if (c0 > 96) c0 = 96;
  if (c1 > 96) c1 = 96;

  float v[3]; int ix[3];
  const float* cv = candV + (size_t)i * 192;
  const int*   ci = candI + (size_t)i * 192;
  #pragma unroll
  for (int qq = 0; qq < 3; ++qq) {
    int s = qq * 64 + lane;
    int hh = (s >= 96) ? 1 : 0;
    int off = s - 96 * hh;
    bool ok = off < (hh ? c1 : c0);
    v[qq]  = ok ? cv[s] : -1e30f;
    ix[qq] = ok ? ci[s] : 0x7fffffff;
  }

  // phase 1: top-28 by mfma value (margin over K=20 makes selection exact after rescore)
  int keepI = 0x7fffffff;
  for (int t = 0; t < 28; ++t) {
    float bv = v[0]; int bi = ix[0]; int bs = 0;
    if (v[1] > bv || (v[1] == bv && ix[1] < bi)) { bv = v[1]; bi = ix[1]; bs = 1; }
    if (v[2] > bv || (v[2] == bv && ix[2] < bi)) { bv = v[2]; bi = ix[2]; bs = 2; }
    int bl = (lane << 2) | bs;
    #pragma unroll
    for (int m = 1; m < 64; m <<= 1) {
      float ov = __shfl_xor(bv, m); int oi = __shfl_xor(bi, m); int ol = __shfl_xor(bl, m);
      if (ov > bv || (ov == bv && oi < bi)) { bv = ov; bi = oi; bl = ol; }
    }
    if ((bl >> 2) == lane) v[bl & 3] = -1e30f;
    if (t == lane) keepI = bi;
  }
  // phase 2: exact fp32 rescore on lanes 0..27
  float rv = -1e30f;
  if (lane < 28) {
    const float* xj = xnf + (size_t)keepI * 128;
    float s = 0.f;
    for (int k4 = 0; k4 < 32; ++k4) {
      vf32x4 a = *(const vf32x4*)&xrow[w][k4 * 4];
      vf32x4 b = *(const vf32x4*)&xj[k4 * 4];
      s += a[0] * b[0] + a[1] * b[1] + a[2] * b[2] + a[3] * b[3];
    }
    rv = s;
  }
  int rix = (lane < 28) ? keepI : 0x7fffffff;
  // phase 3: top-20 by rescored value (tie -> lower index, matching np)
  for (int t = 0; t < 20; ++t) {
    float bv = rv; int bi = rix; int bl = lane;
    #pragma unroll
    for (int m = 1; m < 64; m <<= 1) {
      float ov = __shfl_xor(bv, m); int oi = __shfl_xor(bi, m); int ol = __shfl_xor(bl, m);
      if (ov > bv || (ov == bv && oi < bi)) { bv = ov; bi = oi; bl = ol; }
    }
    if (lane == 0) { topV[(size_t)i * 20 + t] = bv; topI[(size_t)i * 20 + t] = bi; }
    if (bl == lane) rv = -1e30f;
  }
}

// ---------------- precompute U = x@w1[128:], T = x@w1[:128], V = x@uw1[:128] ----------------
__global__ __launch_bounds__(256) void k_pre(
    const u16* __restrict__ xbf, const u16* __restrict__ wcatT,
    float* __restrict__ U, float* __restrict__ T, float* __restrict__ V) {
  const int tid = threadIdx.x, lane = tid & 63, w = tid >> 6;
  const int lr = lane & 15, lg = lane >> 4;
  const int rowbase = blockIdx.x * 64, cb = blockIdx.y;
  const int a = w >> 1, b = w & 1;
  vbf16x8 af[2][4];
  #pragma unroll
  for (int ar = 0; ar < 2; ++ar) {
    const u16* rp = xbf + (size_t)(rowbase + (a * 2 + ar) * 16 + lr) * 128;
    #pragma unroll
    for (int ks = 0; ks < 4; ++ks) af[ar][ks] = *(const vbf16x8*)(rp + ks * 32 + lg * 8);
  }
  vf32x4 z = {0.f, 0.f, 0.f, 0.f};
  vf32x4 acc[2][2] = {{z, z}, {z, z}};
  #pragma unroll
  for (int ks = 0; ks < 4; ++ks) {
    vbf16x8 bf[2];
    #pragma unroll
    for (int cbl = 0; cbl < 2; ++cbl) {
      int gcol = cb * 64 + (b * 2 + cbl) * 16 + lr;
      bf[cbl] = *(const vbf16x8*)(wcatT + (size_t)gcol * 128 + ks * 32 + lg * 8);
    }
    #pragma unroll
    for (int ar = 0; ar < 2; ++ar)
      #pragma unroll
      for (int cbl = 0; cbl < 2; ++cbl)
        acc[ar][cbl] = MFMA16(af[ar][ks], bf[cbl], acc[ar][cbl]);
  }
  #pragma unroll
  for (int ar = 0; ar < 2; ++ar)
    #pragma unroll
    for (int cbl = 0; cbl < 2; ++cbl) {
      int gcol = cb * 64 + (b * 2 + cbl) * 16 + lr;
      #pragma unroll
      for (int r = 0; r < 4; ++r) {
        int grow = rowbase + (a * 2 + ar) * 16 + lg * 4 + r;
        float vv = acc[ar][cbl][r];
        if (gcol < 128)      U[(size_t)grow * 128 + gcol] = vv;
        else if (gcol < 256) T[(size_t)grow * 128 + (gcol - 128)] = vv;
        else                 V[(size_t)grow * 128 + (gcol - 256)] = vv;
      }
    }
}

// ---------------- fused: softmax, G = sum_e s_e*relu(T_i+U_j+b1), h_agg, update MLP ----------------
__global__ __launch_bounds__(256) void k_msg_upd(
    const float* __restrict__ x,
    const float* __restrict__ Uarr, const float* __restrict__ Tarr, const float* __restrict__ Varr,
    const float* __restrict__ topV, const int* __restrict__ topI,
    const float* __restrict__ b1, const float* __restrict__ b2,
    const float* __restrict__ ub1, const float* __restrict__ ub2,
    const u16* __restrict__ w2T, const u16* __restrict__ u1bT, const u16* __restrict__ u2T,
    float* __restrict__ out) {
  __shared__ float wsm[32 * 20];
  __shared__ int   ism[32 * 20];
  __shared__ u16   Gbf[32 * 136];
  __shared__ u16   Hbf[32 * 136];
  const int tid = threadIdx.x, lane = tid & 63, w = tid >> 6;
  const int lr = lane & 15, lg = lane >> 4;
  const int base = blockIdx.x * 32;

  if (tid < 32) { // softmax over rescored top-20 sims
    int i = base + tid;
    float vv[20]; float mx = -1e30f;
    #pragma unroll
    for (int e = 0; e < 20; ++e) { vv[e] = topV[(size_t)i * 20 + e]; mx = fmaxf(mx, vv[e]); }
    float s = 0.f;
    #pragma unroll
    for (int e = 0; e < 20; ++e) { vv[e] = __expf(vv[e] - mx); s += vv[e]; }
    float inv = 1.f / s;
    #pragma unroll
    for (int e = 0; e < 20; ++e) {
      wsm[tid * 20 + e] = vv[e] * inv;
      ism[tid * 20 + e] = topI[(size_t)i * 20 + e];
    }
  }
  __syncthreads();

  { // G step: 8 threads per row, 16 channels each
    int r = tid >> 3, q = tid & 7, ch0 = q * 16;
    int i = base + r;
    vf32x4 z = {0.f, 0.f, 0.f, 0.f};
    vf32x4 tr[4], br[4], acc[4];
    #pragma unroll
    for (int c = 0; c < 4; ++c) {
      tr[c] = *(const vf32x4*)&Tarr[(size_t)i * 128 + ch0 + c * 4];
      br[c] = *(const vf32x4*)&b1[ch0 + c * 4];
      acc[c] = z;
    }
    #pragma unroll 1
    for (int e = 0; e < 20; ++e) {
      int j = ism[r * 20 + e]; float s = wsm[r * 20 + e];
      const vf32x4* up = (const vf32x4*)&Uarr[(size_t)j * 128 + ch0];
      #pragma unroll
      for (int c = 0; c < 4; ++c) {
        vf32x4 u = up[c];
        #pragma unroll
        for (int zz = 0; zz < 4; ++zz) {
          float p = tr[c][zz] + u[zz] + br[c][zz];
          acc[c][zz] += s * fmaxf(p, 0.f);
        }
      }
    }
    #pragma unroll
    for (int c = 0; c < 4; ++c)
      #pragma unroll
      for (int zz = 0; zz < 4; ++zz)
        Gbf[r * 136 + ch0 + c * 4 + zz] = f2bf(acc[c][zz]);
  }
  __syncthreads();

  const int rt = w >> 1, cg = w & 1;
  vf32x4 z4 = {0.f, 0.f, 0.f, 0.f};
  { // GEMM1: h_agg = G @ w2 + b2 -> Hbf
    vf32x4 acc[4] = {z4, z4, z4, z4};
    #pragma unroll
    for (int ks = 0; ks < 4; ++ks) {
      vbf16x8 a = *(const vbf16x8*)&Gbf[(rt * 16 + lr) * 136 + ks * 32 + lg * 8];
      #pragma unroll
      for (int c = 0; c < 4; ++c) {
        int col = (cg * 4 + c) * 16 + lr;
        vbf16x8 bb = *(const vbf16x8*)(w2T + (size_t)col * 128 + ks * 32 + lg * 8);
        acc[c] = MFMA16(a, bb, acc[c]);
      }
    }
    #pragma unroll
    for (int c = 0; c < 4; ++c) {
      int col = (cg * 4 + c) * 16 + lr;
      float bias = b2[col];
      #pragma unroll
      for (int r = 0; r < 4; ++r) {
        int row = rt * 16 + lg * 4 + r;
        Hbf[row * 136 + col] = f2bf(acc[c][r] + bias);
      }
    }
  }
  __syncthreads();
  { // GEMM2: pre = h_agg @ uw1[128:] + V_i + ub1, relu -> Gbf (reused as P)
    vf32x4 acc[4] = {z4, z4, z4, z4};
    #pragma unroll
    for (int ks = 0; ks < 4; ++ks) {
      vbf16x8 a = *(const vbf16x8*)&Hbf[(rt * 16 + lr) * 136 + ks * 32 + lg * 8];
      #pragma unroll
      for (int c = 0; c < 4; ++c) {
        int col = (cg * 4 + c) * 16 + lr;
        vbf16x8 bb = *(const vbf16x8*)(u1bT + (size_t)col * 128 + ks * 32 + lg * 8);
        acc[c] = MFMA16(a, bb, acc[c]);
      }
    }
    #pragma unroll
    for (int c = 0; c < 4; ++c) {
      int col = (cg * 4 + c) * 16 + lr;
      float bias = ub1[col];
      #pragma unroll
      for (int r = 0; r < 4; ++r) {
        int row = rt * 16 + lg * 4 + r;
        float vv = acc[c][r] + Varr[(size_t)(base + row) * 128 + col] + bias;
        Gbf[row * 136 + col] = f2bf(fmaxf(vv, 0.f));
      }
    }
  }
  __syncthreads();
  { // GEMM3: out = x + P @ uw2 + ub2
    vf32x4 acc[4] = {z4, z4, z4, z4};
    #pragma unroll
    for (int ks = 0; ks < 4; ++ks) {
      vbf16x8 a = *(const vbf16x8*)&Gbf[(rt * 16 + lr) * 136 + ks * 32 + lg * 8];
      #pragma unroll
      for (int c = 0; c < 4; ++c) {
        int col = (cg * 4 + c) * 16 + lr;
        vbf16x8 bb = *(const vbf16x8*)(u2T + (size_t)col * 128 + ks * 32 + lg * 8);
        acc[c] = MFMA16(a, bb, acc[c]);
      }
    }
    #pragma unroll
    for (int c = 0; c < 4; ++c) {
      int col = (cg * 4 + c) * 16 + lr;
      float bias = ub2[col];
      #pragma unroll
      for (int r = 0; r < 4; ++r) {
        int row = rt * 16 + lg * 4 + r;
        size_t o = (size_t)(base + row) * 128 + col;
        out[o] = x[o] + acc[c][r] + bias;
      }
    }
  }
}

extern "C" void kernel_launch(void* const* d_in, const int* in_sizes, int n_in,
                              void* d_out, int out_size, void* d_ws, size_t ws_size,
                              hipStream_t stream) {
  (void)in_sizes; (void)n_in; (void)out_size; (void)ws_size;
  const float* x   = (const float*)d_in[0];
  const float* w1  = (const float*)d_in[1];
  const float* b1  = (const float*)d_in[2];
  const float* w2  = (const float*)d_in[3];
  const float* b2  = (const float*)d_in[4];
  const float* uw1 = (const float*)d_in[5];
  const float* ub1 = (const float*)d_in[6];
  const float* uw2 = (const float*)d_in[7];
  const float* ub2 = (const float*)d_in[8];
  float* out = (float*)d_out;
  char* ws = (char*)d_ws;

  u16*   xnbf  = (u16*)(ws + 0);                         // 4 MB
  u16*   xbf   = (u16*)(ws + (4u << 20));                // 4 MB
  float* xnf   = (float*)(ws + (8u << 20));              // 8 MB
  u16*   wcatT = (u16*)(ws + (16u << 20));               // 96 KB
  u16*   w2T   = (u16*)(ws + (16u << 20) + 131072);      // 32 KB
  u16*   u1bT  = (u16*)(ws + (16u << 20) + 163840);      // 32 KB
  u16*   u2T   = (u16*)(ws + (16u << 20) + 196608);      // 32 KB
  int*   cnt2  = (int*)(ws + (16u << 20) + 262144);      // 128 KB
  float* candV = (float*)(ws + (17u << 20));             // 12 MB
  int*   candI = (int*)(ws + (30u << 20));               // 12 MB
  float* topV  = (float*)(ws + (43u << 20));             // 1.31 MB
  int*   topI  = (int*)(ws + (45u << 20));               // 1.31 MB
  float* Uarr  = (float*)(ws + (47u << 20));             // 8 MB
  float* Tarr  = (float*)(ws + (55u << 20));             // 8 MB
  float* Varr  = (float*)(ws + (63u << 20));             // 8 MB -> total 71 MB

  hipLaunchKernelGGL(k_prep_w, dim3(384), dim3(256), 0, stream,
                     w1, w2, uw1, uw2, wcatT, w2T, u1bT, u2T);
  hipLaunchKernelGGL(k_norm, dim3(4096), dim3(256), 0, stream, x, xnf, xnbf, xbf, cnt2);
  hipLaunchKernelGGL(k_sim_topk, dim3(512), dim3(256), 0, stream, xnbf, candV, candI, cnt2);
  hipLaunchKernelGGL(k_select, dim3(4096), dim3(256), 0, stream, xnf, candV, candI, cnt2, topV, topI);
  hipLaunchKernelGGL(k_pre, dim3(256, 6), dim3(256), 0, stream, xbf, wcatT, Uarr, Tarr, Varr);
  hipLaunchKernelGGL(k_msg_upd, dim3(512), dim3(256), 0, stream,
                     x, Uarr, Tarr, Varr, topV, topI, b1, b2, ub1, ub2, w2T, u1bT, u2T, out);
}

// Round 4
// 449.309 us; speedup vs baseline: 2.1733x; 1.6923x over previous
//
#include <hip/hip_runtime.h>

typedef unsigned short u16;
typedef short vbf16x8 __attribute__((ext_vector_type(8)));   // 8 bf16 as shorts (4 VGPR)
typedef float vf32x4 __attribute__((ext_vector_type(4)));
typedef int vi32x4 __attribute__((ext_vector_type(4)));

#define MFMA16(a,b,c) __builtin_amdgcn_mfma_f32_16x16x32_bf16((a),(b),(c),0,0,0)

__device__ __forceinline__ u16 f2bf(float f) {
  union { float f; unsigned u; } c; c.f = f;
  unsigned r = c.u + 0x7fffu + ((c.u >> 16) & 1u);
  return (u16)(r >> 16);
}

// ---------------- prep: weight transposes (bf16) ----------------
__global__ __launch_bounds__(256) void k_prep_w(
    const float* __restrict__ w1, const float* __restrict__ w2,
    const float* __restrict__ u1, const float* __restrict__ u2,
    u16* __restrict__ wcatT, u16* __restrict__ w2T,
    u16* __restrict__ u1bT, u16* __restrict__ u2T) {
  int id = blockIdx.x * 256 + threadIdx.x;
  if (id < 49152) {
    int n = id >> 7, k = id & 127;
    float v;
    if (n < 128) v = w1[(128 + k) * 128 + n];
    else if (n < 256) v = w1[k * 128 + (n - 128)];
    else v = u1[k * 128 + (n - 256)];
    wcatT[id] = f2bf(v);
  } else {
    int id2 = id - 49152;
    int m = id2 >> 14, r = id2 & 16383;
    int n = r >> 7, k = r & 127;
    if (m == 0) w2T[r] = f2bf(w2[k * 128 + n]);
    else if (m == 1) u1bT[r] = f2bf(u1[(128 + k) * 128 + n]);
    else u2T[r] = f2bf(u2[k * 128 + n]);
  }
}

// ---------------- norms: xnf (f32), xbf (raw bf16), xnt (normalized bf16, MFMA-granule-tiled) --------
// xnt layout: granule (row j, ks, lg) = bf16 elems [ks*32+lg*8 .. +8) of row j stored at
// u16 offset (j>>4)*2048 + ks*512 + lg*128 + (j&15)*8. Serves A- and B-fragments directly.
__global__ __launch_bounds__(256) void k_norm(
    const float* __restrict__ x, float* __restrict__ xnf,
    u16* __restrict__ xnt, u16* __restrict__ xbf, int* __restrict__ cnt) {
  __shared__ u16 buf[4][128];
  int tid = threadIdx.x;
  int gid = blockIdx.x * 256 + tid;
  if (gid < 16384) cnt[gid] = 0;
  int lane = tid & 63, w = tid >> 6;
  int row = blockIdx.x * 4 + w;
  size_t b = (size_t)row * 128;
  float v0 = x[b + lane], v1 = x[b + 64 + lane];
  float ss = v0 * v0 + v1 * v1;
  #pragma unroll
  for (int m = 32; m > 0; m >>= 1) ss += __shfl_xor(ss, m);
  float d = fmaxf(sqrtf(ss), 1e-8f);
  float n0 = v0 / d, n1 = v1 / d;
  xnf[b + lane] = n0; xnf[b + 64 + lane] = n1;
  xbf[b + lane] = f2bf(v0); xbf[b + 64 + lane] = f2bf(v1);
  buf[w][lane] = f2bf(n0); buf[w][64 + lane] = f2bf(n1);
  __syncthreads();
  if (tid < 64) {
    int r = tid >> 4, g = tid & 15;
    int grow = blockIdx.x * 4 + r;
    vi32x4 d4 = *(const vi32x4*)&buf[r][g * 8];
    *(vi32x4*)&xnt[(size_t)(grow >> 4) * 2048 + (g >> 2) * 512 + (g & 3) * 128 + (grow & 15) * 8] = d4;
  }
}

// branchless per-lane top-3 update
#define TOP3(M1, M2, M3, V) { \
  bool g1 = (V) > (M1), g2 = (V) > (M2), g3 = (V) > (M3); \
  (M3) = g2 ? (M2) : (g3 ? (V) : (M3)); \
  (M2) = g1 ? (M1) : (g2 ? (V) : (M2)); \
  (M1) = g1 ? (V) : (M1); }

// ---------------- pass 1: per-(row,seg) lane-top-3 samples -> sampV[row][seg][48] ------------------
// Block: 128 rows (4 waves x 32 rows) x one 2048-col segment. No LDS, no barriers.
// The 8 segs x 16 lanes x top-3 = 384 samples per row feed k_theta's exact 28th-of-union.
__global__ __launch_bounds__(256, 4) void k_sim1(
    const u16* __restrict__ xnt, float* __restrict__ sampV) {
  const int tid = threadIdx.x, lane = tid & 63, w = tid >> 6;
  const int lr = lane & 15, lg = lane >> 4;
  const int seg = blockIdx.x & 7, rbk = blockIdx.x >> 3;
  const int rowbase = rbk * 128 + w * 32;

  vbf16x8 af[2][4];
  #pragma unroll
  for (int a = 0; a < 2; ++a) {
    const u16* tp = xnt + (size_t)((rowbase >> 4) + a) * 2048;
    #pragma unroll
    for (int ks = 0; ks < 4; ++ks)
      af[a][ks] = *(const vbf16x8*)(tp + ks * 512 + lg * 128 + lr * 8);
  }

  float m1[2][4], m2[2][4], m3[2][4];
  #pragma unroll
  for (int a = 0; a < 2; ++a)
    #pragma unroll
    for (int r = 0; r < 4; ++r) { m1[a][r] = -1e30f; m2[a][r] = -1e30f; m3[a][r] = -1e30f; }

  const u16* segp = xnt + (size_t)(seg * 128) * 2048;
  vbf16x8 bc[4], bn[4];
  #pragma unroll
  for (int ks = 0; ks < 4; ++ks) bc[ks] = *(const vbf16x8*)(segp + ks * 512 + lane * 8);

#define SIM1STEP(B) { \
  vf32x4 a0 = {0.f,0.f,0.f,0.f}, a1 = {0.f,0.f,0.f,0.f}; \
  _Pragma("unroll") \
  for (int ks = 0; ks < 4; ++ks) { a0 = MFMA16(af[0][ks], (B)[ks], a0); a1 = MFMA16(af[1][ks], (B)[ks], a1); } \
  _Pragma("unroll") \
  for (int r = 0; r < 4; ++r) { TOP3(m1[0][r], m2[0][r], m3[0][r], a0[r]); TOP3(m1[1][r], m2[1][r], m3[1][r], a1[r]); } }

  #pragma unroll 1
  for (int t2 = 0; t2 < 64; ++t2) {
    { const u16* tp1 = segp + (size_t)(2 * t2 + 1) * 2048;
      #pragma unroll
      for (int ks = 0; ks < 4; ++ks) bn[ks] = *(const vbf16x8*)(tp1 + ks * 512 + lane * 8); }
    SIM1STEP(bc);
    { int nt = (t2 < 63) ? (2 * t2 + 2) : 127;
      const u16* tp2 = segp + (size_t)nt * 2048;
      #pragma unroll
      for (int ks = 0; ks < 4; ++ks) bc[ks] = *(const vbf16x8*)(tp2 + ks * 512 + lane * 8); }
    SIM1STEP(bn);
  }

  // dump 48 raw samples per (row, seg): [row*384 + seg*48 + s*16 + lr]
  #pragma unroll
  for (int a = 0; a < 2; ++a)
    #pragma unroll
    for (int r = 0; r < 4; ++r) {
      int row = rowbase + a * 16 + lg * 4 + r;
      float* dp = sampV + (size_t)row * 384 + seg * 48;
      dp[lr] = m1[a][r]; dp[16 + lr] = m2[a][r]; dp[32 + lr] = m3[a][r];
    }
}

// ---------------- theta: exact 28th-largest of the 384-sample union per row ------------------------
// theta <= true 28th mfma value (subset order statistic over full-row stream-top-3 union);
// union misses top values only on >=4-deep stream collisions (28 balls in 128 bins -> rare),
// so theta ~ true 28th..34th -> capture count ~30-40 << cap 96.
__global__ __launch_bounds__(256) void k_theta(
    const float* __restrict__ sampV, float* __restrict__ thbuf) {
  const int lane = threadIdx.x & 63, w = threadIdx.x >> 6;
  const int row = blockIdx.x * 4 + w;
  const float* sp = sampV + (size_t)row * 384;
  float v[6];
  #pragma unroll
  for (int q = 0; q < 6; ++q) v[q] = sp[q * 64 + lane];
  float g = -1e30f;
  #pragma unroll 1
  for (int t = 0; t < 28; ++t) {
    float loc = v[0];
    #pragma unroll
    for (int q = 1; q < 6; ++q) loc = fmaxf(loc, v[q]);
    g = loc;
    #pragma unroll
    for (int mm = 1; mm < 64; mm <<= 1) g = fmaxf(g, __shfl_xor(g, mm));
    #pragma unroll
    for (int q = 0; q < 6; ++q) v[q] = (v[q] == g) ? -1e30f : v[q];
  }
  if (lane == 0) thbuf[row] = g;
}

// ---------------- pass 2: bitwise-identical MFMAs, capture v >= theta(row) -------------------------
__global__ __launch_bounds__(256, 4) void k_sim2(
    const u16* __restrict__ xnt, const float* __restrict__ thbuf,
    float* __restrict__ candV, int* __restrict__ candI, int* __restrict__ cnt) {
  const int tid = threadIdx.x, lane = tid & 63, w = tid >> 6;
  const int lr = lane & 15, lg = lane >> 4;
  const int seg = blockIdx.x & 7, rbk = blockIdx.x >> 3;
  const int rowbase = rbk * 128 + w * 32;

  vbf16x8 af[2][4];
  #pragma unroll
  for (int a = 0; a < 2; ++a) {
    const u16* tp = xnt + (size_t)((rowbase >> 4) + a) * 2048;
    #pragma unroll
    for (int ks = 0; ks < 4; ++ks)
      af[a][ks] = *(const vbf16x8*)(tp + ks * 512 + lg * 128 + lr * 8);
  }

  float th0[4], th1[4];
  #pragma unroll
  for (int r = 0; r < 4; ++r) {
    th0[r] = thbuf[rowbase + lg * 4 + r];
    th1[r] = thbuf[rowbase + 16 + lg * 4 + r];
  }

  const u16* segp = xnt + (size_t)(seg * 128) * 2048;
  vbf16x8 bc[4], bn[4];
  #pragma unroll
  for (int ks = 0; ks < 4; ++ks) bc[ks] = *(const vbf16x8*)(segp + ks * 512 + lane * 8);

#define SIM2STEP(B, COLB) { \
  vf32x4 a0 = {0.f,0.f,0.f,0.f}, a1 = {0.f,0.f,0.f,0.f}; \
  _Pragma("unroll") \
  for (int ks = 0; ks < 4; ++ks) { a0 = MFMA16(af[0][ks], (B)[ks], a0); a1 = MFMA16(af[1][ks], (B)[ks], a1); } \
  _Pragma("unroll") \
  for (int r = 0; r < 4; ++r) { \
    if (a0[r] >= th0[r]) { int row = rowbase + lg * 4 + r; \
      int s = atomicAdd(&cnt[row], 1); \
      if (s < 96) { candV[(size_t)row * 96 + s] = a0[r]; candI[(size_t)row * 96 + s] = (COLB) + lr; } } \
    if (a1[r] >= th1[r]) { int row = rowbase + 16 + lg * 4 + r; \
      int s = atomicAdd(&cnt[row], 1); \
      if (s < 96) { candV[(size_t)row * 96 + s] = a1[r]; candI[(size_t)row * 96 + s] = (COLB) + lr; } } } }

  const int colseg = seg * 2048;
  #pragma unroll 1
  for (int t2 = 0; t2 < 64; ++t2) {
    { const u16* tp1 = segp + (size_t)(2 * t2 + 1) * 2048;
      #pragma unroll
      for (int ks = 0; ks < 4; ++ks) bn[ks] = *(const vbf16x8*)(tp1 + ks * 512 + lane * 8); }
    SIM2STEP(bc, colseg + (2 * t2) * 16);
    { int nt = (t2 < 63) ? (2 * t2 + 2) : 127;
      const u16* tp2 = segp + (size_t)nt * 2048;
      #pragma unroll
      for (int ks = 0; ks < 4; ++ks) bc[ks] = *(const vbf16x8*)(tp2 + ks * 512 + lane * 8); }
    SIM2STEP(bn, colseg + (2 * t2 + 1) * 16);
  }
}

// ---------------- merge candidates -> mfma-top-28 -> fp32 rescore -> top-20 ----------------
__global__ __launch_bounds__(256) void k_select(
    const float* __restrict__ xnf,
    const float* __restrict__ candV, const int* __restrict__ candI,
    const int* __restrict__ cnt,
    float* __restrict__ topV, int* __restrict__ topI) {
  __shared__ float xrow[4][128];
  const int tid = threadIdx.x, lane = tid & 63, w = tid >> 6;
  const int i = blockIdx.x * 4 + w;
  xrow[w][lane] = xnf[(size_t)i * 128 + lane];
  xrow[w][64 + lane] = xnf[(size_t)i * 128 + 64 + lane];
  __syncthreads();

  int c = cnt[i]; if (c > 96) c = 96;
  const float* cv = candV + (size_t)i * 96;
  const int*   ci = candI + (size_t)i * 96;
  float v0 = (lane < c) ? cv[lane] : -1e30f;
  int  i0 = (lane < c) ? ci[lane] : 0x7fffffff;
  int s1 = 64 + lane;
  float v1 = (s1 < c) ? cv[s1] : -1e30f;
  int  i1 = (s1 < c) ? ci[s1] : 0x7fffffff;

  // phase 1: top-28 by mfma value (margin over K=20 makes selection exact after rescore)
  int keepI = 0x7fffffff;
  for (int t = 0; t < 28; ++t) {
    float bv = v0; int bi = i0; int bs = 0;
    if (v1 > bv || (v1 == bv && i1 < bi)) { bv = v1; bi = i1; bs = 1; }
    int bl = (lane << 1) | bs;
    #pragma unroll
    for (int m = 1; m < 64; m <<= 1) {
      float ov = __shfl_xor(bv, m); int oi = __shfl_xor(bi, m); int ol = __shfl_xor(bl, m);
      if (ov > bv || (ov == bv && oi < bi)) { bv = ov; bi = oi; bl = ol; }
    }
    int win = ((bl >> 1) == lane);
    v0 = (win && !(bl & 1)) ? -1e30f : v0;
    v1 = (win && (bl & 1)) ? -1e30f : v1;
    if (t == lane) keepI = bi;
  }
  // phase 2: exact fp32 rescore on lanes 0..27
  float rv = -1e30f;
  int keepC = keepI & 16383;  // safety clamp; cnt >= 28 is guaranteed by theta construction
  if (lane < 28) {
    const float* xj = xnf + (size_t)keepC * 128;
    float s = 0.f;
    for (int k4 = 0; k4 < 32; ++k4) {
      vf32x4 a = *(const vf32x4*)&xrow[w][k4 * 4];
      vf32x4 b = *(const vf32x4*)&xj[k4 * 4];
      s += a[0] * b[0] + a[1] * b[1] + a[2] * b[2] + a[3] * b[3];
    }
    rv = s;
  }
  int rix = (lane < 28) ? keepI : 0x7fffffff;
  // phase 3: top-20 by rescored value (tie -> lower index, matching np)
  for (int t = 0; t < 20; ++t) {
    float bv = rv; int bi = rix; int bl = lane;
    #pragma unroll
    for (int m = 1; m < 64; m <<= 1) {
      float ov = __shfl_xor(bv, m); int oi = __shfl_xor(bi, m); int ol = __shfl_xor(bl, m);
      if (ov > bv || (ov == bv && oi < bi)) { bv = ov; bi = oi; bl = ol; }
    }
    if (lane == 0) { topV[(size_t)i * 20 + t] = bv; topI[(size_t)i * 20 + t] = bi; }
    if (bl == lane) rv = -1e30f;
  }
}

// ---------------- precompute U = x@w1[128:], T = x@w1[:128], V = x@uw1[:128] ----------------
__global__ __launch_bounds__(256) void k_pre(
    const u16* __restrict__ xbf, const u16* __restrict__ wcatT,
    float* __restrict__ U, float* __restrict__ T, float* __restrict__ V) {
  const int tid = threadIdx.x, lane = tid & 63, w = tid >> 6;
  const int lr = lane & 15, lg = lane >> 4;
  const int rowbase = blockIdx.x * 64, cb = blockIdx.y;
  const int a = w >> 1, b = w & 1;
  vbf16x8 af[2][4];
  #pragma unroll
  for (int ar = 0; ar < 2; ++ar) {
    const u16* rp = xbf + (size_t)(rowbase + (a * 2 + ar) * 16 + lr) * 128;
    #pragma unroll
    for (int ks = 0; ks < 4; ++ks) af[ar][ks] = *(const vbf16x8*)(rp + ks * 32 + lg * 8);
  }
  vf32x4 z = {0.f, 0.f, 0.f, 0.f};
  vf32x4 acc[2][2] = {{z, z}, {z, z}};
  #pragma unroll
  for (int ks = 0; ks < 4; ++ks) {
    vbf16x8 bf[2];
    #pragma unroll
    for (int cbl = 0; cbl < 2; ++cbl) {
      int gcol = cb * 64 + (b * 2 + cbl) * 16 + lr;
      bf[cbl] = *(const vbf16x8*)(wcatT + (size_t)gcol * 128 + ks * 32 + lg * 8);
    }
    #pragma unroll
    for (int ar = 0; ar < 2; ++ar)
      #pragma unroll
      for (int cbl = 0; cbl < 2; ++cbl)
        acc[ar][cbl] = MFMA16(af[ar][ks], bf[cbl], acc[ar][cbl]);
  }
  #pragma unroll
  for (int ar = 0; ar < 2; ++ar)
    #pragma unroll
    for (int cbl = 0; cbl < 2; ++cbl) {
      int gcol = cb * 64 + (b * 2 + cbl) * 16 + lr;
      #pragma unroll
      for (int r = 0; r < 4; ++r) {
        int grow = rowbase + (a * 2 + ar) * 16 + lg * 4 + r;
        float vv = acc[ar][cbl][r];
        if (gcol < 128)      U[(size_t)grow * 128 + gcol] = vv;
        else if (gcol < 256) T[(size_t)grow * 128 + (gcol - 128)] = vv;
        else                 V[(size_t)grow * 128 + (gcol - 256)] = vv;
      }
    }
}

// ---------------- fused: softmax, G = sum_e s_e*relu(T_i+U_j+b1), h_agg, update MLP ----------------
__global__ __launch_bounds__(256) void k_msg_upd(
    const float* __restrict__ x,
    const float* __restrict__ Uarr, const float* __restrict__ Tarr, const float* __restrict__ Varr,
    const float* __restrict__ topV, const int* __restrict__ topI,
    const float* __restrict__ b1, const float* __restrict__ b2,
    const float* __restrict__ ub1, const float* __restrict__ ub2,
    const u16* __restrict__ w2T, const u16* __restrict__ u1bT, const u16* __restrict__ u2T,
    float* __restrict__ out) {
  __shared__ float wsm[32 * 20];
  __shared__ int   ism[32 * 20];
  __shared__ u16   Gbf[32 * 136];
  __shared__ u16   Hbf[32 * 136];
  const int tid = threadIdx.x, lane = tid & 63, w = tid >> 6;
  const int lr = lane & 15, lg = lane >> 4;
  const int base = blockIdx.x * 32;

  if (tid < 32) { // softmax over rescored top-20 sims
    int i = base + tid;
    float vv[20]; float mx = -1e30f;
    #pragma unroll
    for (int e = 0; e < 20; ++e) { vv[e] = topV[(size_t)i * 20 + e]; mx = fmaxf(mx, vv[e]); }
    float s = 0.f;
    #pragma unroll
    for (int e = 0; e < 20; ++e) { vv[e] = __expf(vv[e] - mx); s += vv[e]; }
    float inv = 1.f / s;
    #pragma unroll
    for (int e = 0; e < 20; ++e) {
      wsm[tid * 20 + e] = vv[e] * inv;
      ism[tid * 20 + e] = topI[(size_t)i * 20 + e];
    }
  }
  __syncthreads();

  { // G step: 8 threads per row, 16 channels each
    int r = tid >> 3, q = tid & 7, ch0 = q * 16;
    int i = base + r;
    vf32x4 z = {0.f, 0.f, 0.f, 0.f};
    vf32x4 tr[4], br[4], acc[4];
    #pragma unroll
    for (int c = 0; c < 4; ++c) {
      tr[c] = *(const vf32x4*)&Tarr[(size_t)i * 128 + ch0 + c * 4];
      br[c] = *(const vf32x4*)&b1[ch0 + c * 4];
      acc[c] = z;
    }
    #pragma unroll 1
    for (int e = 0; e < 20; ++e) {
      int j = ism[r * 20 + e]; float s = wsm[r * 20 + e];
      const vf32x4* up = (const vf32x4*)&Uarr[(size_t)j * 128 + ch0];
      #pragma unroll
      for (int c = 0; c < 4; ++c) {
        vf32x4 u = up[c];
        #pragma unroll
        for (int zz = 0; zz < 4; ++zz) {
          float p = tr[c][zz] + u[zz] + br[c][zz];
          acc[c][zz] += s * fmaxf(p, 0.f);
        }
      }
    }
    #pragma unroll
    for (int c = 0; c < 4; ++c)
      #pragma unroll
      for (int zz = 0; zz < 4; ++zz)
        Gbf[r * 136 + ch0 + c * 4 + zz] = f2bf(acc[c][zz]);
  }
  __syncthreads();

  const int rt = w >> 1, cg = w & 1;
  vf32x4 z4 = {0.f, 0.f, 0.f, 0.f};
  { // GEMM1: h_agg = G @ w2 + b2 -> Hbf
    vf32x4 acc[4] = {z4, z4, z4, z4};
    #pragma unroll
    for (int ks = 0; ks < 4; ++ks) {
      vbf16x8 a = *(const vbf16x8*)&Gbf[(rt * 16 + lr) * 136 + ks * 32 + lg * 8];
      #pragma unroll
      for (int c = 0; c < 4; ++c) {
        int col = (cg * 4 + c) * 16 + lr;
        vbf16x8 bb = *(const vbf16x8*)(w2T + (size_t)col * 128 + ks * 32 + lg * 8);
        acc[c] = MFMA16(a, bb, acc[c]);
      }
    }
    #pragma unroll
    for (int c = 0; c < 4; ++c) {
      int col = (cg * 4 + c) * 16 + lr;
      float bias = b2[col];
      #pragma unroll
      for (int r = 0; r < 4; ++r) {
        int row = rt * 16 + lg * 4 + r;
        Hbf[row * 136 + col] = f2bf(acc[c][r] + bias);
      }
    }
  }
  __syncthreads();
  { // GEMM2: pre = h_agg @ uw1[128:] + V_i + ub1, relu -> Gbf (reused as P)
    vf32x4 acc[4] = {z4, z4, z4, z4};
    #pragma unroll
    for (int ks = 0; ks < 4; ++ks) {
      vbf16x8 a = *(const vbf16x8*)&Hbf[(rt * 16 + lr) * 136 + ks * 32 + lg * 8];
      #pragma unroll
      for (int c = 0; c < 4; ++c) {
        int col = (cg * 4 + c) * 16 + lr;
        vbf16x8 bb = *(const vbf16x8*)(u1bT + (size_t)col * 128 + ks * 32 + lg * 8);
        acc[c] = MFMA16(a, bb, acc[c]);
      }
    }
    #pragma unroll
    for (int c = 0; c < 4; ++c) {
      int col = (cg * 4 + c) * 16 + lr;
      float bias = ub1[col];
      #pragma unroll
      for (int r = 0; r < 4; ++r) {
        int row = rt * 16 + lg * 4 + r;
        float vv = acc[c][r] + Varr[(size_t)(base + row) * 128 + col] + bias;
        Gbf[row * 136 + col] = f2bf(fmaxf(vv, 0.f));
      }
    }
  }
  __syncthreads();
  { // GEMM3: out = x + P @ uw2 + ub2
    vf32x4 acc[4] = {z4, z4, z4, z4};
    #pragma unroll
    for (int ks = 0; ks < 4; ++ks) {
      vbf16x8 a = *(const vbf16x8*)&Gbf[(rt * 16 + lr) * 136 + ks * 32 + lg * 8];
      #pragma unroll
      for (int c = 0; c < 4; ++c) {
        int col = (cg * 4 + c) * 16 + lr;
        vbf16x8 bb = *(const vbf16x8*)(u2T + (size_t)col * 128 + ks * 32 + lg * 8);
        acc[c] = MFMA16(a, bb, acc[c]);
      }
    }
    #pragma unroll
    for (int c = 0; c < 4; ++c) {
      int col = (cg * 4 + c) * 16 + lr;
      float bias = ub2[col];
      #pragma unroll
      for (int r = 0; r < 4; ++r) {
        int row = rt * 16 + lg * 4 + r;
        size_t o = (size_t)(base + row) * 128 + col;
        out[o] = x[o] + acc[c][r] + bias;
      }
    }
  }
}

extern "C" void kernel_launch(void* const* d_in, const int* in_sizes, int n_in,
                              void* d_out, int out_size, void* d_ws, size_t ws_size,
                              hipStream_t stream) {
  (void)in_sizes; (void)n_in; (void)out_size; (void)ws_size;
  const float* x   = (const float*)d_in[0];
  const float* w1  = (const float*)d_in[1];
  const float* b1  = (const float*)d_in[2];
  const float* w2  = (const float*)d_in[3];
  const float* b2  = (const float*)d_in[4];
  const float* uw1 = (const float*)d_in[5];
  const float* ub1 = (const float*)d_in[6];
  const float* uw2 = (const float*)d_in[7];
  const float* ub2 = (const float*)d_in[8];
  float* out = (float*)d_out;
  char* ws = (char*)d_ws;

  // Live ranges: sampV [41M,66.2M) dies after k_theta; candV/candI/topV/topI overlay it.
  // High-water 66.2 MB <= 71 MB (proven available in round 1).
  u16*      xnt   = (u16*)(ws + 0);                         // 4 MB (granule-tiled xn)
  u16*      xbf   = (u16*)(ws + (4u << 20));                // 4 MB
  float*    xnf   = (float*)(ws + (8u << 20));              // 8 MB
  u16*      wcatT = (u16*)(ws + (16u << 20));               // 96 KB
  u16*      w2T   = (u16*)(ws + (16u << 20) + 131072);      // 32 KB
  u16*      u1bT  = (u16*)(ws + (16u << 20) + 163840);      // 32 KB
  u16*      u2T   = (u16*)(ws + (16u << 20) + 196608);      // 32 KB
  int*      cnt   = (int*)(ws + (16u << 20) + 262144);      // 64 KB
  float*    thbuf = (float*)(ws + (16u << 20) + 327680);    // 64 KB
  float*    Uarr  = (float*)(ws + (17u << 20));             // 8 MB
  float*    Tarr  = (float*)(ws + (25u << 20));             // 8 MB
  float*    Varr  = (float*)(ws + (33u << 20));             // 8 MB
  float*    sampV = (float*)(ws + (41u << 20));             // 25.2 MB (transient)
  float*    candV = (float*)(ws + (41u << 20));             // 6.3 MB (after sampV dead)
  int*      candI = (int*)(ws + (48u << 20));               // 6.3 MB
  float*    topV  = (float*)(ws + (55u << 20));             // 1.31 MB
  int*      topI  = (int*)(ws + (57u << 20));               // 1.31 MB

  hipLaunchKernelGGL(k_prep_w, dim3(384), dim3(256), 0, stream,
                     w1, w2, uw1, uw2, wcatT, w2T, u1bT, u2T);
  hipLaunchKernelGGL(k_norm, dim3(4096), dim3(256), 0, stream, x, xnf, xnt, xbf, cnt);
  hipLaunchKernelGGL(k_sim1, dim3(1024), dim3(256), 0, stream, xnt, sampV);
  hipLaunchKernelGGL(k_theta, dim3(4096), dim3(256), 0, stream, sampV, thbuf);
  hipLaunchKernelGGL(k_sim2, dim3(1024), dim3(256), 0, stream, xnt, thbuf, candV, candI, cnt);
  hipLaunchKernelGGL(k_select, dim3(4096), dim3(256), 0, stream, xnf, candV, candI, cnt, topV, topI);
  hipLaunchKernelGGL(k_pre, dim3(256, 6), dim3(256), 0, stream, xbf, wcatT, Uarr, Tarr, Varr);
  hipLaunchKernelGGL(k_msg_upd, dim3(512), dim3(256), 0, stream,
                     x, Uarr, Tarr, Varr, topV, topI, b1, b2, ub1, ub2, w2T, u1bT, u2T, out);
}

// Round 5
// 322.519 us; speedup vs baseline: 3.0276x; 1.3931x over previous
//
#include <hip/hip_runtime.h>

typedef unsigned short u16;
typedef short vbf16x8 __attribute__((ext_vector_type(8)));   // 8 bf16 as shorts (4 VGPR)
typedef float vf32x4 __attribute__((ext_vector_type(4)));
typedef int vi32x4 __attribute__((ext_vector_type(4)));

#define MFMA16(a,b,c) __builtin_amdgcn_mfma_f32_16x16x32_bf16((a),(b),(c),0,0,0)

__device__ __forceinline__ u16 f2bf(float f) {
  union { float f; unsigned u; } c; c.f = f;
  unsigned r = c.u + 0x7fffu + ((c.u >> 16) & 1u);
  return (u16)(r >> 16);
}

// ---------------- prep: weight transposes (bf16) ----------------
__global__ __launch_bounds__(256) void k_prep_w(
    const float* __restrict__ w1, const float* __restrict__ w2,
    const float* __restrict__ u1, const float* __restrict__ u2,
    u16* __restrict__ wcatT, u16* __restrict__ w2T,
    u16* __restrict__ u1bT, u16* __restrict__ u2T) {
  int id = blockIdx.x * 256 + threadIdx.x;
  if (id < 49152) {
    int n = id >> 7, k = id & 127;
    float v;
    if (n < 128) v = w1[(128 + k) * 128 + n];
    else if (n < 256) v = w1[k * 128 + (n - 128)];
    else v = u1[k * 128 + (n - 256)];
    wcatT[id] = f2bf(v);
  } else {
    int id2 = id - 49152;
    int m = id2 >> 14, r = id2 & 16383;
    int n = r >> 7, k = r & 127;
    if (m == 0) w2T[r] = f2bf(w2[k * 128 + n]);
    else if (m == 1) u1bT[r] = f2bf(u1[(128 + k) * 128 + n]);
    else u2T[r] = f2bf(u2[k * 128 + n]);
  }
}

// ---------------- norms: xnf (f32), xbf (raw bf16), xnt (normalized bf16, MFMA-granule-tiled) --------
// xnt layout: granule (row j, ks, lg) = bf16 elems [ks*32+lg*8 .. +8) of row j stored at
// u16 offset (j>>4)*2048 + ks*512 + lg*128 + (j&15)*8. Serves A- and B-fragments directly.
__global__ __launch_bounds__(256) void k_norm(
    const float* __restrict__ x, float* __restrict__ xnf,
    u16* __restrict__ xnt, u16* __restrict__ xbf, int* __restrict__ cnt) {
  __shared__ u16 buf[4][128];
  int tid = threadIdx.x;
  int gid = blockIdx.x * 256 + tid;
  if (gid < 16384) cnt[gid] = 0;
  int lane = tid & 63, w = tid >> 6;
  int row = blockIdx.x * 4 + w;
  size_t b = (size_t)row * 128;
  float v0 = x[b + lane], v1 = x[b + 64 + lane];
  float ss = v0 * v0 + v1 * v1;
  #pragma unroll
  for (int m = 32; m > 0; m >>= 1) ss += __shfl_xor(ss, m);
  float d = fmaxf(sqrtf(ss), 1e-8f);
  float n0 = v0 / d, n1 = v1 / d;
  xnf[b + lane] = n0; xnf[b + 64 + lane] = n1;
  xbf[b + lane] = f2bf(v0); xbf[b + 64 + lane] = f2bf(v1);
  buf[w][lane] = f2bf(n0); buf[w][64 + lane] = f2bf(n1);
  __syncthreads();
  if (tid < 64) {
    int r = tid >> 4, g = tid & 15;
    int grow = blockIdx.x * 4 + r;
    vi32x4 d4 = *(const vi32x4*)&buf[r][g * 8];
    *(vi32x4*)&xnt[(size_t)(grow >> 4) * 2048 + (g >> 2) * 512 + (g & 3) * 128 + (grow & 15) * 8] = d4;
  }
}

// branchless per-lane top-3 update
#define TOP3(M1, M2, M3, V) { \
  bool g1 = (V) > (M1), g2 = (V) > (M2), g3 = (V) > (M3); \
  (M3) = g2 ? (M2) : (g3 ? (V) : (M3)); \
  (M2) = g1 ? (M1) : (g2 ? (V) : (M2)); \
  (M1) = g1 ? (V) : (M1); }

// ---------------- pass 1: per-(row,seg) lane-top-3 samples -> sampV[row][seg][48] ------------------
// Block: 128 rows (4 waves x 32 rows) x one 2048-col segment. No LDS, no barriers.
// The 8 segs x 16 lanes x top-3 = 384 samples per row feed k_theta's exact 28th-of-union.
__global__ __launch_bounds__(256, 4) void k_sim1(
    const u16* __restrict__ xnt, float* __restrict__ sampV) {
  const int tid = threadIdx.x, lane = tid & 63, w = tid >> 6;
  const int lr = lane & 15, lg = lane >> 4;
  const int seg = blockIdx.x & 7, rbk = blockIdx.x >> 3;
  const int rowbase = rbk * 128 + w * 32;

  vbf16x8 af[2][4];
  #pragma unroll
  for (int a = 0; a < 2; ++a) {
    const u16* tp = xnt + (size_t)((rowbase >> 4) + a) * 2048;
    #pragma unroll
    for (int ks = 0; ks < 4; ++ks)
      af[a][ks] = *(const vbf16x8*)(tp + ks * 512 + lg * 128 + lr * 8);
  }

  float m1[2][4], m2[2][4], m3[2][4];
  #pragma unroll
  for (int a = 0; a < 2; ++a)
    #pragma unroll
    for (int r = 0; r < 4; ++r) { m1[a][r] = -1e30f; m2[a][r] = -1e30f; m3[a][r] = -1e30f; }

  const u16* segp = xnt + (size_t)(seg * 128) * 2048;
  vbf16x8 bc[4], bn[4];
  #pragma unroll
  for (int ks = 0; ks < 4; ++ks) bc[ks] = *(const vbf16x8*)(segp + ks * 512 + lane * 8);

#define SIM1STEP(B) { \
  vf32x4 a0 = {0.f,0.f,0.f,0.f}, a1 = {0.f,0.f,0.f,0.f}; \
  _Pragma("unroll") \
  for (int ks = 0; ks < 4; ++ks) { a0 = MFMA16(af[0][ks], (B)[ks], a0); a1 = MFMA16(af[1][ks], (B)[ks], a1); } \
  _Pragma("unroll") \
  for (int r = 0; r < 4; ++r) { TOP3(m1[0][r], m2[0][r], m3[0][r], a0[r]); TOP3(m1[1][r], m2[1][r], m3[1][r], a1[r]); } }

  #pragma unroll 1
  for (int t2 = 0; t2 < 64; ++t2) {
    { const u16* tp1 = segp + (size_t)(2 * t2 + 1) * 2048;
      #pragma unroll
      for (int ks = 0; ks < 4; ++ks) bn[ks] = *(const vbf16x8*)(tp1 + ks * 512 + lane * 8); }
    SIM1STEP(bc);
    { int nt = (t2 < 63) ? (2 * t2 + 2) : 127;
      const u16* tp2 = segp + (size_t)nt * 2048;
      #pragma unroll
      for (int ks = 0; ks < 4; ++ks) bc[ks] = *(const vbf16x8*)(tp2 + ks * 512 + lane * 8); }
    SIM1STEP(bn);
  }

  // dump 48 raw samples per (row, seg): [row*384 + seg*48 + s*16 + lr]
  #pragma unroll
  for (int a = 0; a < 2; ++a)
    #pragma unroll
    for (int r = 0; r < 4; ++r) {
      int row = rowbase + a * 16 + lg * 4 + r;
      float* dp = sampV + (size_t)row * 384 + seg * 48;
      dp[lr] = m1[a][r]; dp[16 + lr] = m2[a][r]; dp[32 + lr] = m3[a][r];
    }
}

// ---------------- theta: exact 28th-largest of the 384-sample union per row ------------------------
// theta <= true 28th mfma value (subset order statistic over full-row stream-top-3 union);
// union misses top values only on >=4-deep stream collisions (28 balls in 128 bins -> rare),
// so theta ~ true 28th..34th -> capture count ~30-40 << cap 96.
__global__ __launch_bounds__(256) void k_theta(
    const float* __restrict__ sampV, float* __restrict__ thbuf) {
  const int lane = threadIdx.x & 63, w = threadIdx.x >> 6;
  const int row = blockIdx.x * 4 + w;
  const float* sp = sampV + (size_t)row * 384;
  float v[6];
  #pragma unroll
  for (int q = 0; q < 6; ++q) v[q] = sp[q * 64 + lane];
  float g = -1e30f;
  #pragma unroll 1
  for (int t = 0; t < 28; ++t) {
    float loc = v[0];
    #pragma unroll
    for (int q = 1; q < 6; ++q) loc = fmaxf(loc, v[q]);
    g = loc;
    #pragma unroll
    for (int mm = 1; mm < 64; mm <<= 1) g = fmaxf(g, __shfl_xor(g, mm));
    #pragma unroll
    for (int q = 0; q < 6; ++q) v[q] = (v[q] == g) ? -1e30f : v[q];
  }
  if (lane == 0) thbuf[row] = g;
}

// ---------------- pass 2: bitwise-identical MFMAs, capture col indices with v >= theta(row) --------
__global__ __launch_bounds__(256, 4) void k_sim2(
    const u16* __restrict__ xnt, const float* __restrict__ thbuf,
    int* __restrict__ candI, int* __restrict__ cnt) {
  const int tid = threadIdx.x, lane = tid & 63, w = tid >> 6;
  const int lr = lane & 15, lg = lane >> 4;
  const int seg = blockIdx.x & 7, rbk = blockIdx.x >> 3;
  const int rowbase = rbk * 128 + w * 32;

  vbf16x8 af[2][4];
  #pragma unroll
  for (int a = 0; a < 2; ++a) {
    const u16* tp = xnt + (size_t)((rowbase >> 4) + a) * 2048;
    #pragma unroll
    for (int ks = 0; ks < 4; ++ks)
      af[a][ks] = *(const vbf16x8*)(tp + ks * 512 + lg * 128 + lr * 8);
  }

  float th0[4], th1[4];
  #pragma unroll
  for (int r = 0; r < 4; ++r) {
    th0[r] = thbuf[rowbase + lg * 4 + r];
    th1[r] = thbuf[rowbase + 16 + lg * 4 + r];
  }

  const u16* segp = xnt + (size_t)(seg * 128) * 2048;
  vbf16x8 bc[4], bn[4];
  #pragma unroll
  for (int ks = 0; ks < 4; ++ks) bc[ks] = *(const vbf16x8*)(segp + ks * 512 + lane * 8);

#define SIM2STEP(B, COLB) { \
  vf32x4 a0 = {0.f,0.f,0.f,0.f}, a1 = {0.f,0.f,0.f,0.f}; \
  _Pragma("unroll") \
  for (int ks = 0; ks < 4; ++ks) { a0 = MFMA16(af[0][ks], (B)[ks], a0); a1 = MFMA16(af[1][ks], (B)[ks], a1); } \
  _Pragma("unroll") \
  for (int r = 0; r < 4; ++r) { \
    if (a0[r] >= th0[r]) { int row = rowbase + lg * 4 + r; \
      int s = atomicAdd(&cnt[row], 1); \
      if (s < 96) candI[(size_t)row * 96 + s] = (COLB) + lr; } \
    if (a1[r] >= th1[r]) { int row = rowbase + 16 + lg * 4 + r; \
      int s = atomicAdd(&cnt[row], 1); \
      if (s < 96) candI[(size_t)row * 96 + s] = (COLB) + lr; } } }

  const int colseg = seg * 2048;
  #pragma unroll 1
  for (int t2 = 0; t2 < 64; ++t2) {
    { const u16* tp1 = segp + (size_t)(2 * t2 + 1) * 2048;
      #pragma unroll
      for (int ks = 0; ks < 4; ++ks) bn[ks] = *(const vbf16x8*)(tp1 + ks * 512 + lane * 8); }
    SIM2STEP(bc, colseg + (2 * t2) * 16);
    { int nt = (t2 < 63) ? (2 * t2 + 2) : 127;
      const u16* tp2 = segp + (size_t)nt * 2048;
      #pragma unroll
      for (int ks = 0; ks < 4; ++ks) bc[ks] = *(const vbf16x8*)(tp2 + ks * 512 + lane * 8); }
    SIM2STEP(bn, colseg + (2 * t2 + 1) * 16);
  }
}

// ---------------- select: rescore ALL candidates (fp32, half-wave each), rank-count top-20 ---------
// Candidate set (v_mfma >= theta) is a superset of mfma-top-28 -> rescore-margin guarantee holds.
// Output order is arbitrary (downstream softmax+sum is order-independent); set matches np's
// top_k by (fp32 value, lower index) strict total order.
__global__ __launch_bounds__(256) void k_select(
    const float* __restrict__ xnf,
    const int* __restrict__ candI, const int* __restrict__ cnt,
    float* __restrict__ topV, int* __restrict__ topI) {
  __shared__ float svals[4][96];
  __shared__ int   sidx[4][96];
  const int tid = threadIdx.x, lane = tid & 63, w = tid >> 6;
  const int i = blockIdx.x * 4 + w;
  const int q = lane >> 5, ll = lane & 31;
  int c = cnt[i]; if (c > 96) c = 96;
  const int* ci = candI + (size_t)i * 96;
  vf32x4 xi = *(const vf32x4*)&xnf[(size_t)i * 128 + ll * 4];
  // rescore: half-wave (32 lanes) per candidate, two candidates per iteration
  #pragma unroll 1
  for (int sp = 0; sp < c; sp += 2) {
    int s2 = sp + q;
    bool val = s2 < c;
    int j = ci[val ? s2 : sp];
    vf32x4 xj = *(const vf32x4*)&xnf[(size_t)j * 128 + ll * 4];
    float p = xi[0] * xj[0] + xi[1] * xj[1] + xi[2] * xj[2] + xi[3] * xj[3];
    #pragma unroll
    for (int m = 1; m < 32; m <<= 1) p += __shfl_xor(p, m);
    if (ll == 0 && val) { svals[w][s2] = p; sidx[w][s2] = j; }
  }
  __syncthreads();
  // rank by pairwise counting (LDS broadcast reads, no tournaments)
  float v0 = -1e30f; int i0 = 0x7fffffff;
  if (lane < c) { v0 = svals[w][lane]; i0 = sidx[w][lane]; }
  float v1 = -1e30f; int i1 = 0x7fffffff;
  if (64 + lane < c) { v1 = svals[w][64 + lane]; i1 = sidx[w][64 + lane]; }
  int rank0 = 0, rank1 = 0;
  #pragma unroll 1
  for (int s = 0; s < c; ++s) {
    float vs = svals[w][s]; int is = sidx[w][s];
    rank0 += (vs > v0 || (vs == v0 && is < i0)) ? 1 : 0;
    rank1 += (vs > v1 || (vs == v1 && is < i1)) ? 1 : 0;
  }
  bool win0 = (lane < c) && (rank0 < 20);
  unsigned long long b0 = __ballot(win0);
  int pos0 = __popcll(b0 & ((1ull << lane) - 1ull));
  if (win0) { topV[(size_t)i * 20 + pos0] = v0; topI[(size_t)i * 20 + pos0] = i0; }
  int base1 = __popcll(b0);
  bool win1 = (64 + lane < c) && (rank1 < 20);
  unsigned long long b1 = __ballot(win1);
  int pos1 = base1 + __popcll(b1 & ((1ull << lane) - 1ull));
  if (win1) { topV[(size_t)i * 20 + pos1] = v1; topI[(size_t)i * 20 + pos1] = i1; }
}

// ---------------- precompute U = x@w1[128:], T = x@w1[:128], V = x@uw1[:128] ----------------
__global__ __launch_bounds__(256) void k_pre(
    const u16* __restrict__ xbf, const u16* __restrict__ wcatT,
    float* __restrict__ U, float* __restrict__ T, float* __restrict__ V) {
  const int tid = threadIdx.x, lane = tid & 63, w = tid >> 6;
  const int lr = lane & 15, lg = lane >> 4;
  const int rowbase = blockIdx.x * 64, cb = blockIdx.y;
  const int a = w >> 1, b = w & 1;
  vbf16x8 af[2][4];
  #pragma unroll
  for (int ar = 0; ar < 2; ++ar) {
    const u16* rp = xbf + (size_t)(rowbase + (a * 2 + ar) * 16 + lr) * 128;
    #pragma unroll
    for (int ks = 0; ks < 4; ++ks) af[ar][ks] = *(const vbf16x8*)(rp + ks * 32 + lg * 8);
  }
  vf32x4 z = {0.f, 0.f, 0.f, 0.f};
  vf32x4 acc[2][2] = {{z, z}, {z, z}};
  #pragma unroll
  for (int ks = 0; ks < 4; ++ks) {
    vbf16x8 bf[2];
    #pragma unroll
    for (int cbl = 0; cbl < 2; ++cbl) {
      int gcol = cb * 64 + (b * 2 + cbl) * 16 + lr;
      bf[cbl] = *(const vbf16x8*)(wcatT + (size_t)gcol * 128 + ks * 32 + lg * 8);
    }
    #pragma unroll
    for (int ar = 0; ar < 2; ++ar)
      #pragma unroll
      for (int cbl = 0; cbl < 2; ++cbl)
        acc[ar][cbl] = MFMA16(af[ar][ks], bf[cbl], acc[ar][cbl]);
  }
  #pragma unroll
  for (int ar = 0; ar < 2; ++ar)
    #pragma unroll
    for (int cbl = 0; cbl < 2; ++cbl) {
      int gcol = cb * 64 + (b * 2 + cbl) * 16 + lr;
      #pragma unroll
      for (int r = 0; r < 4; ++r) {
        int grow = rowbase + (a * 2 + ar) * 16 + lg * 4 + r;
        float vv = acc[ar][cbl][r];
        if (gcol < 128)      U[(size_t)grow * 128 + gcol] = vv;
        else if (gcol < 256) T[(size_t)grow * 128 + (gcol - 128)] = vv;
        else                 V[(size_t)grow * 128 + (gcol - 256)] = vv;
      }
    }
}

// ---------------- fused: softmax, G = sum_e s_e*relu(T_i+U_j+b1), h_agg, update MLP ----------------
__global__ __launch_bounds__(256) void k_msg_upd(
    const float* __restrict__ x,
    const float* __restrict__ Uarr, const float* __restrict__ Tarr, const float* __restrict__ Varr,
    const float* __restrict__ topV, const int* __restrict__ topI,
    const float* __restrict__ b1, const float* __restrict__ b2,
    const float* __restrict__ ub1, const float* __restrict__ ub2,
    const u16* __restrict__ w2T, const u16* __restrict__ u1bT, const u16* __restrict__ u2T,
    float* __restrict__ out) {
  __shared__ float wsm[32 * 20];
  __shared__ int   ism[32 * 20];
  __shared__ u16   Gbf[32 * 136];
  __shared__ u16   Hbf[32 * 136];
  const int tid = threadIdx.x, lane = tid & 63, w = tid >> 6;
  const int lr = lane & 15, lg = lane >> 4;
  const int base = blockIdx.x * 32;

  if (tid < 32) { // softmax over rescored top-20 sims (order-independent)
    int i = base + tid;
    float vv[20]; float mx = -1e30f;
    #pragma unroll
    for (int e = 0; e < 20; ++e) { vv[e] = topV[(size_t)i * 20 + e]; mx = fmaxf(mx, vv[e]); }
    float s = 0.f;
    #pragma unroll
    for (int e = 0; e < 20; ++e) { vv[e] = __expf(vv[e] - mx); s += vv[e]; }
    float inv = 1.f / s;
    #pragma unroll
    for (int e = 0; e < 20; ++e) {
      wsm[tid * 20 + e] = vv[e] * inv;
      ism[tid * 20 + e] = topI[(size_t)i * 20 + e];
    }
  }
  __syncthreads();

  { // G step: 8 threads per row, 16 channels each
    int r = tid >> 3, q = tid & 7, ch0 = q * 16;
    int i = base + r;
    vf32x4 z = {0.f, 0.f, 0.f, 0.f};
    vf32x4 tr[4], br[4], acc[4];
    #pragma unroll
    for (int c = 0; c < 4; ++c) {
      tr[c] = *(const vf32x4*)&Tarr[(size_t)i * 128 + ch0 + c * 4];
      br[c] = *(const vf32x4*)&b1[ch0 + c * 4];
      acc[c] = z;
    }
    #pragma unroll 1
    for (int e = 0; e < 20; ++e) {
      int j = ism[r * 20 + e]; float s = wsm[r * 20 + e];
      const vf32x4* up = (const vf32x4*)&Uarr[(size_t)j * 128 + ch0];
      #pragma unroll
      for (int c = 0; c < 4; ++c) {
        vf32x4 u = up[c];
        #pragma unroll
        for (int zz = 0; zz < 4; ++zz) {
          float p = tr[c][zz] + u[zz] + br[c][zz];
          acc[c][zz] += s * fmaxf(p, 0.f);
        }
      }
    }
    #pragma unroll
    for (int c = 0; c < 4; ++c)
      #pragma unroll
      for (int zz = 0; zz < 4; ++zz)
        Gbf[r * 136 + ch0 + c * 4 + zz] = f2bf(acc[c][zz]);
  }
  __syncthreads();

  const int rt = w >> 1, cg = w & 1;
  vf32x4 z4 = {0.f, 0.f, 0.f, 0.f};
  { // GEMM1: h_agg = G @ w2 + b2 -> Hbf
    vf32x4 acc[4] = {z4, z4, z4, z4};
    #pragma unroll
    for (int ks = 0; ks < 4; ++ks) {
      vbf16x8 a = *(const vbf16x8*)&Gbf[(rt * 16 + lr) * 136 + ks * 32 + lg * 8];
      #pragma unroll
      for (int c = 0; c < 4; ++c) {
        int col = (cg * 4 + c) * 16 + lr;
        vbf16x8 bb = *(const vbf16x8*)(w2T + (size_t)col * 128 + ks * 32 + lg * 8);
        acc[c] = MFMA16(a, bb, acc[c]);
      }
    }
    #pragma unroll
    for (int c = 0; c < 4; ++c) {
      int col = (cg * 4 + c) * 16 + lr;
      float bias = b2[col];
      #pragma unroll
      for (int r = 0; r < 4; ++r) {
        int row = rt * 16 + lg * 4 + r;
        Hbf[row * 136 + col] = f2bf(acc[c][r] + bias);
      }
    }
  }
  __syncthreads();
  { // GEMM2: pre = h_agg @ uw1[128:] + V_i + ub1, relu -> Gbf (reused as P)
    vf32x4 acc[4] = {z4, z4, z4, z4};
    #pragma unroll
    for (int ks = 0; ks < 4; ++ks) {
      vbf16x8 a = *(const vbf16x8*)&Hbf[(rt * 16 + lr) * 136 + ks * 32 + lg * 8];
      #pragma unroll
      for (int c = 0; c < 4; ++c) {
        int col = (cg * 4 + c) * 16 + lr;
        vbf16x8 bb = *(const vbf16x8*)(u1bT + (size_t)col * 128 + ks * 32 + lg * 8);
        acc[c] = MFMA16(a, bb, acc[c]);
      }
    }
    #pragma unroll
    for (int c = 0; c < 4; ++c) {
      int col = (cg * 4 + c) * 16 + lr;
      float bias = ub1[col];
      #pragma unroll
      for (int r = 0; r < 4; ++r) {
        int row = rt * 16 + lg * 4 + r;
        float vv = acc[c][r] + Varr[(size_t)(base + row) * 128 + col] + bias;
        Gbf[row * 136 + col] = f2bf(fmaxf(vv, 0.f));
      }
    }
  }
  __syncthreads();
  { // GEMM3: out = x + P @ uw2 + ub2
    vf32x4 acc[4] = {z4, z4, z4, z4};
    #pragma unroll
    for (int ks = 0; ks < 4; ++ks) {
      vbf16x8 a = *(const vbf16x8*)&Gbf[(rt * 16 + lr) * 136 + ks * 32 + lg * 8];
      #pragma unroll
      for (int c = 0; c < 4; ++c) {
        int col = (cg * 4 + c) * 16 + lr;
        vbf16x8 bb = *(const vbf16x8*)(u2T + (size_t)col * 128 + ks * 32 + lg * 8);
        acc[c] = MFMA16(a, bb, acc[c]);
      }
    }
    #pragma unroll
    for (int c = 0; c < 4; ++c) {
      int col = (cg * 4 + c) * 16 + lr;
      float bias = ub2[col];
      #pragma unroll
      for (int r = 0; r < 4; ++r) {
        int row = rt * 16 + lg * 4 + r;
        size_t o = (size_t)(base + row) * 128 + col;
        out[o] = x[o] + acc[c][r] + bias;
      }
    }
  }
}

extern "C" void kernel_launch(void* const* d_in, const int* in_sizes, int n_in,
                              void* d_out, int out_size, void* d_ws, size_t ws_size,
                              hipStream_t stream) {
  (void)in_sizes; (void)n_in; (void)out_size; (void)ws_size;
  const float* x   = (const float*)d_in[0];
  const float* w1  = (const float*)d_in[1];
  const float* b1  = (const float*)d_in[2];
  const float* w2  = (const float*)d_in[3];
  const float* b2  = (const float*)d_in[4];
  const float* uw1 = (const float*)d_in[5];
  const float* ub1 = (const float*)d_in[6];
  const float* uw2 = (const float*)d_in[7];
  const float* ub2 = (const float*)d_in[8];
  float* out = (float*)d_out;
  char* ws = (char*)d_ws;

  // Live ranges: sampV [41M,66.2M) dies after k_theta; candI/topV/topI overlay it.
  u16*      xnt   = (u16*)(ws + 0);                         // 4 MB (granule-tiled xn)
  u16*      xbf   = (u16*)(ws + (4u << 20));                // 4 MB
  float*    xnf   = (float*)(ws + (8u << 20));              // 8 MB
  u16*      wcatT = (u16*)(ws + (16u << 20));               // 96 KB
  u16*      w2T   = (u16*)(ws + (16u << 20) + 131072);      // 32 KB
  u16*      u1bT  = (u16*)(ws + (16u << 20) + 163840);      // 32 KB
  u16*      u2T   = (u16*)(ws + (16u << 20) + 196608);      // 32 KB
  int*      cnt   = (int*)(ws + (16u << 20) + 262144);      // 64 KB
  float*    thbuf = (float*)(ws + (16u << 20) + 327680);    // 64 KB
  float*    Uarr  = (float*)(ws + (17u << 20));             // 8 MB
  float*    Tarr  = (float*)(ws + (25u << 20));             // 8 MB
  float*    Varr  = (float*)(ws + (33u << 20));             // 8 MB
  float*    sampV = (float*)(ws + (41u << 20));             // 25.2 MB (transient)
  int*      candI = (int*)(ws + (41u << 20));               // 6.3 MB (after sampV dead)
  float*    topV  = (float*)(ws + (48u << 20));             // 1.31 MB
  int*      topI  = (int*)(ws + (50u << 20));               // 1.31 MB

  hipLaunchKernelGGL(k_prep_w, dim3(384), dim3(256), 0, stream,
                     w1, w2, uw1, uw2, wcatT, w2T, u1bT, u2T);
  hipLaunchKernelGGL(k_norm, dim3(4096), dim3(256), 0, stream, x, xnf, xnt, xbf, cnt);
  hipLaunchKernelGGL(k_sim1, dim3(1024), dim3(256), 0, stream, xnt, sampV);
  hipLaunchKernelGGL(k_theta, dim3(4096), dim3(256), 0, stream, sampV, thbuf);
  hipLaunchKernelGGL(k_sim2, dim3(1024), dim3(256), 0, stream, xnt, thbuf, candI, cnt);
  hipLaunchKernelGGL(k_select, dim3(4096), dim3(256), 0, stream, xnf, candI, cnt, topV, topI);
  hipLaunchKernelGGL(k_pre, dim3(256, 6), dim3(256), 0, stream, xbf, wcatT, Uarr, Tarr, Varr);
  hipLaunchKernelGGL(k_msg_upd, dim3(512), dim3(256), 0, stream,
                     x, Uarr, Tarr, Varr, topV, topI, b1, b2, ub1, ub2, w2T, u1bT, u2T, out);
}

// Round 6
// 313.275 us; speedup vs baseline: 3.1170x; 1.0295x over previous
//
#include <hip/hip_runtime.h>

typedef unsigned short u16;
typedef short vbf16x8 __attribute__((ext_vector_type(8)));   // 8 bf16 as shorts (4 VGPR)
typedef float vf32x4 __attribute__((ext_vector_type(4)));
typedef int vi32x4 __attribute__((ext_vector_type(4)));

#define MFMA16(a,b,c) __builtin_amdgcn_mfma_f32_16x16x32_bf16((a),(b),(c),0,0,0)

__device__ __forceinline__ u16 f2bf(float f) {
  union { float f; unsigned u; } c; c.f = f;
  unsigned r = c.u + 0x7fffu + ((c.u >> 16) & 1u);
  return (u16)(r >> 16);
}

// ---------------- prep: weight transposes (bf16) ----------------
__global__ __launch_bounds__(256) void k_prep_w(
    const float* __restrict__ w1, const float* __restrict__ w2,
    const float* __restrict__ u1, const float* __restrict__ u2,
    u16* __restrict__ wcatT, u16* __restrict__ w2T,
    u16* __restrict__ u1bT, u16* __restrict__ u2T) {
  int id = blockIdx.x * 256 + threadIdx.x;
  if (id < 49152) {
    int n = id >> 7, k = id & 127;
    float v;
    if (n < 128) v = w1[(128 + k) * 128 + n];
    else if (n < 256) v = w1[k * 128 + (n - 128)];
    else v = u1[k * 128 + (n - 256)];
    wcatT[id] = f2bf(v);
  } else {
    int id2 = id - 49152;
    int m = id2 >> 14, r = id2 & 16383;
    int n = r >> 7, k = r & 127;
    if (m == 0) w2T[r] = f2bf(w2[k * 128 + n]);
    else if (m == 1) u1bT[r] = f2bf(u1[(128 + k) * 128 + n]);
    else u2T[r] = f2bf(u2[k * 128 + n]);
  }
}

// ---------------- norms: xnf (f32), xbf (raw bf16), xnt (normalized bf16, MFMA-granule-tiled) --------
// xnt layout: granule (row j, ks, lg) = bf16 elems [ks*32+lg*8 .. +8) of row j stored at
// u16 offset (j>>4)*2048 + ks*512 + lg*128 + (j&15)*8. Serves A- and B-fragments directly.
__global__ __launch_bounds__(256) void k_norm(
    const float* __restrict__ x, float* __restrict__ xnf,
    u16* __restrict__ xnt, u16* __restrict__ xbf, int* __restrict__ cnt) {
  __shared__ u16 buf[4][128];
  int tid = threadIdx.x;
  int gid = blockIdx.x * 256 + tid;
  if (gid < 16384) cnt[gid] = 0;
  int lane = tid & 63, w = tid >> 6;
  int row = blockIdx.x * 4 + w;
  size_t b = (size_t)row * 128;
  float v0 = x[b + lane], v1 = x[b + 64 + lane];
  float ss = v0 * v0 + v1 * v1;
  #pragma unroll
  for (int m = 32; m > 0; m >>= 1) ss += __shfl_xor(ss, m);
  float d = fmaxf(sqrtf(ss), 1e-8f);
  float n0 = v0 / d, n1 = v1 / d;
  xnf[b + lane] = n0; xnf[b + 64 + lane] = n1;
  xbf[b + lane] = f2bf(v0); xbf[b + 64 + lane] = f2bf(v1);
  buf[w][lane] = f2bf(n0); buf[w][64 + lane] = f2bf(n1);
  __syncthreads();
  if (tid < 64) {
    int r = tid >> 4, g = tid & 15;
    int grow = blockIdx.x * 4 + r;
    vi32x4 d4 = *(const vi32x4*)&buf[r][g * 8];
    *(vi32x4*)&xnt[(size_t)(grow >> 4) * 2048 + (g >> 2) * 512 + (g & 3) * 128 + (grow & 15) * 8] = d4;
  }
}

// branchless per-lane top-2 update
#define TOP2(M1, M2, V) { \
  bool g1 = (V) > (M1), g2 = (V) > (M2); \
  (M2) = g1 ? (M1) : (g2 ? (V) : (M2)); \
  (M1) = g1 ? (V) : (M1); }

// ---------------- pass 1: per-(row,seg) lane-top-2 samples -> sampV[row][seg][32] ------------------
// Block: 128 rows (4 waves x 32 rows) x one 1024-col segment. No LDS, no barriers.
// Grid 2048 = 8 blocks/CU -> 8 waves/SIMD (VGPR <= 64) to hide L2 latency.
// 16 segs x 16 lanes x top-2 = 512 samples per row feed k_theta's 28th-of-union.
__global__ __launch_bounds__(256, 4) void k_sim1(
    const u16* __restrict__ xnt, float* __restrict__ sampV) {
  const int tid = threadIdx.x, lane = tid & 63, w = tid >> 6;
  const int lr = lane & 15, lg = lane >> 4;
  const int seg = blockIdx.x & 15, rbk = blockIdx.x >> 4;
  const int rowbase = rbk * 128 + w * 32;

  vbf16x8 af[2][4];
  #pragma unroll
  for (int a = 0; a < 2; ++a) {
    const u16* tp = xnt + (size_t)((rowbase >> 4) + a) * 2048;
    #pragma unroll
    for (int ks = 0; ks < 4; ++ks)
      af[a][ks] = *(const vbf16x8*)(tp + ks * 512 + lg * 128 + lr * 8);
  }

  float m1[2][4], m2[2][4];
  #pragma unroll
  for (int a = 0; a < 2; ++a)
    #pragma unroll
    for (int r = 0; r < 4; ++r) { m1[a][r] = -1e30f; m2[a][r] = -1e30f; }

  const u16* segp = xnt + (size_t)(seg * 64) * 2048;
  vbf16x8 bc[4], bn[4];
  #pragma unroll
  for (int ks = 0; ks < 4; ++ks) bc[ks] = *(const vbf16x8*)(segp + ks * 512 + lane * 8);

#define SIM1STEP(B) { \
  vf32x4 a0 = {0.f,0.f,0.f,0.f}, a1 = {0.f,0.f,0.f,0.f}; \
  _Pragma("unroll") \
  for (int ks = 0; ks < 4; ++ks) { a0 = MFMA16(af[0][ks], (B)[ks], a0); a1 = MFMA16(af[1][ks], (B)[ks], a1); } \
  _Pragma("unroll") \
  for (int r = 0; r < 4; ++r) { TOP2(m1[0][r], m2[0][r], a0[r]); TOP2(m1[1][r], m2[1][r], a1[r]); } }

  #pragma unroll 1
  for (int t2 = 0; t2 < 32; ++t2) {
    { const u16* tp1 = segp + (size_t)(2 * t2 + 1) * 2048;
      #pragma unroll
      for (int ks = 0; ks < 4; ++ks) bn[ks] = *(const vbf16x8*)(tp1 + ks * 512 + lane * 8); }
    SIM1STEP(bc);
    { int nt = (t2 < 31) ? (2 * t2 + 2) : 63;
      const u16* tp2 = segp + (size_t)nt * 2048;
      #pragma unroll
      for (int ks = 0; ks < 4; ++ks) bc[ks] = *(const vbf16x8*)(tp2 + ks * 512 + lane * 8); }
    SIM1STEP(bn);
  }

  // dump 32 raw samples per (row, seg): [row*512 + seg*32 + s*16 + lr]
  #pragma unroll
  for (int a = 0; a < 2; ++a)
    #pragma unroll
    for (int r = 0; r < 4; ++r) {
      int row = rowbase + a * 16 + lg * 4 + r;
      float* dp = sampV + (size_t)row * 512 + seg * 32;
      dp[lr] = m1[a][r]; dp[16 + lr] = m2[a][r];
    }
}

// ---------------- theta: 28th-largest of the 512-sample union per row ------------------------------
// theta <= true 28th mfma value (subset order statistic over stream-top-2 union; 256 streams).
// A stream holding >=3 of the true top-28 slides theta down a rank (P ~ 0.05/row) -> capture
// ~30-40 << cap 128.
__global__ __launch_bounds__(256) void k_theta(
    const float* __restrict__ sampV, float* __restrict__ thbuf) {
  const int lane = threadIdx.x & 63, w = threadIdx.x >> 6;
  const int row = blockIdx.x * 4 + w;
  const float* sp = sampV + (size_t)row * 512;
  float v[8];
  #pragma unroll
  for (int q = 0; q < 8; ++q) v[q] = sp[q * 64 + lane];
  float g = -1e30f;
  #pragma unroll 1
  for (int t = 0; t < 28; ++t) {
    float loc = v[0];
    #pragma unroll
    for (int q = 1; q < 8; ++q) loc = fmaxf(loc, v[q]);
    g = loc;
    #pragma unroll
    for (int mm = 1; mm < 64; mm <<= 1) g = fmaxf(g, __shfl_xor(g, mm));
    #pragma unroll
    for (int q = 0; q < 8; ++q) v[q] = (v[q] == g) ? -1e30f : v[q];
  }
  if (lane == 0) thbuf[row] = g;
}

// ---------------- pass 2: bitwise-identical MFMAs, capture col indices with v >= theta(row) --------
__global__ __launch_bounds__(256, 4) void k_sim2(
    const u16* __restrict__ xnt, const float* __restrict__ thbuf,
    int* __restrict__ candI, int* __restrict__ cnt) {
  const int tid = threadIdx.x, lane = tid & 63, w = tid >> 6;
  const int lr = lane & 15, lg = lane >> 4;
  const int seg = blockIdx.x & 15, rbk = blockIdx.x >> 4;
  const int rowbase = rbk * 128 + w * 32;

  vbf16x8 af[2][4];
  #pragma unroll
  for (int a = 0; a < 2; ++a) {
    const u16* tp = xnt + (size_t)((rowbase >> 4) + a) * 2048;
    #pragma unroll
    for (int ks = 0; ks < 4; ++ks)
      af[a][ks] = *(const vbf16x8*)(tp + ks * 512 + lg * 128 + lr * 8);
  }

  float th0[4], th1[4];
  #pragma unroll
  for (int r = 0; r < 4; ++r) {
    th0[r] = thbuf[rowbase + lg * 4 + r];
    th1[r] = thbuf[rowbase + 16 + lg * 4 + r];
  }

  const u16* segp = xnt + (size_t)(seg * 64) * 2048;
  vbf16x8 bc[4], bn[4];
  #pragma unroll
  for (int ks = 0; ks < 4; ++ks) bc[ks] = *(const vbf16x8*)(segp + ks * 512 + lane * 8);

#define SIM2STEP(B, COLB) { \
  vf32x4 a0 = {0.f,0.f,0.f,0.f}, a1 = {0.f,0.f,0.f,0.f}; \
  _Pragma("unroll") \
  for (int ks = 0; ks < 4; ++ks) { a0 = MFMA16(af[0][ks], (B)[ks], a0); a1 = MFMA16(af[1][ks], (B)[ks], a1); } \
  _Pragma("unroll") \
  for (int r = 0; r < 4; ++r) { \
    if (a0[r] >= th0[r]) { int row = rowbase + lg * 4 + r; \
      int s = atomicAdd(&cnt[row], 1); \
      if (s < 128) candI[(size_t)row * 128 + s] = (COLB) + lr; } \
    if (a1[r] >= th1[r]) { int row = rowbase + 16 + lg * 4 + r; \
      int s = atomicAdd(&cnt[row], 1); \
      if (s < 128) candI[(size_t)row * 128 + s] = (COLB) + lr; } } }

  const int colseg = seg * 1024;
  #pragma unroll 1
  for (int t2 = 0; t2 < 32; ++t2) {
    { const u16* tp1 = segp + (size_t)(2 * t2 + 1) * 2048;
      #pragma unroll
      for (int ks = 0; ks < 4; ++ks) bn[ks] = *(const vbf16x8*)(tp1 + ks * 512 + lane * 8); }
    SIM2STEP(bc, colseg + (2 * t2) * 16);
    { int nt = (t2 < 31) ? (2 * t2 + 2) : 63;
      const u16* tp2 = segp + (size_t)nt * 2048;
      #pragma unroll
      for (int ks = 0; ks < 4; ++ks) bc[ks] = *(const vbf16x8*)(tp2 + ks * 512 + lane * 8); }
    SIM2STEP(bn, colseg + (2 * t2 + 1) * 16);
  }
}

// ---------------- select: rescore ALL candidates (fp32, half-wave each), rank-count top-20 ---------
// Candidate set (v_mfma >= theta) is a superset of mfma-top-28 -> rescore-margin guarantee holds.
// Output order is arbitrary (downstream softmax+sum is order-independent); set matches np's
// top_k by (fp32 value, lower index) strict total order.
__global__ __launch_bounds__(256) void k_select(
    const float* __restrict__ xnf,
    const int* __restrict__ candI, const int* __restrict__ cnt,
    float* __restrict__ topV, int* __restrict__ topI) {
  __shared__ float svals[4][128];
  __shared__ int   sidx[4][128];
  const int tid = threadIdx.x, lane = tid & 63, w = tid >> 6;
  const int i = blockIdx.x * 4 + w;
  const int q = lane >> 5, ll = lane & 31;
  int c = cnt[i]; if (c > 128) c = 128;
  const int* ci = candI + (size_t)i * 128;
  vf32x4 xi = *(const vf32x4*)&xnf[(size_t)i * 128 + ll * 4];
  // rescore: half-wave (32 lanes) per candidate, two candidates per iteration
  #pragma unroll 1
  for (int sp = 0; sp < c; sp += 2) {
    int s2 = sp + q;
    bool val = s2 < c;
    int j = ci[val ? s2 : sp];
    vf32x4 xj = *(const vf32x4*)&xnf[(size_t)j * 128 + ll * 4];
    float p = xi[0] * xj[0] + xi[1] * xj[1] + xi[2] * xj[2] + xi[3] * xj[3];
    #pragma unroll
    for (int m = 1; m < 32; m <<= 1) p += __shfl_xor(p, m);
    if (ll == 0 && val) { svals[w][s2] = p; sidx[w][s2] = j; }
  }
  __syncthreads();
  // rank by pairwise counting (LDS broadcast reads, no tournaments)
  float v0 = -1e30f; int i0 = 0x7fffffff;
  if (lane < c) { v0 = svals[w][lane]; i0 = sidx[w][lane]; }
  float v1 = -1e30f; int i1 = 0x7fffffff;
  if (64 + lane < c) { v1 = svals[w][64 + lane]; i1 = sidx[w][64 + lane]; }
  int rank0 = 0, rank1 = 0;
  #pragma unroll 1
  for (int s = 0; s < c; ++s) {
    float vs = svals[w][s]; int is = sidx[w][s];
    rank0 += (vs > v0 || (vs == v0 && is < i0)) ? 1 : 0;
    rank1 += (vs > v1 || (vs == v1 && is < i1)) ? 1 : 0;
  }
  bool win0 = (lane < c) && (rank0 < 20);
  unsigned long long b0 = __ballot(win0);
  int pos0 = __popcll(b0 & ((1ull << lane) - 1ull));
  if (win0) { topV[(size_t)i * 20 + pos0] = v0; topI[(size_t)i * 20 + pos0] = i0; }
  int base1 = __popcll(b0);
  bool win1 = (64 + lane < c) && (rank1 < 20);
  unsigned long long b1 = __ballot(win1);
  int pos1 = base1 + __popcll(b1 & ((1ull << lane) - 1ull));
  if (win1) { topV[(size_t)i * 20 + pos1] = v1; topI[(size_t)i * 20 + pos1] = i1; }
}

// ---------------- precompute U = x@w1[128:], T = x@w1[:128], V = x@uw1[:128] ----------------
__global__ __launch_bounds__(256) void k_pre(
    const u16* __restrict__ xbf, const u16* __restrict__ wcatT,
    float* __restrict__ U, float* __restrict__ T, float* __restrict__ V) {
  const int tid = threadIdx.x, lane = tid & 63, w = tid >> 6;
  const int lr = lane & 15, lg = lane >> 4;
  const int rowbase = blockIdx.x * 64, cb = blockIdx.y;
  const int a = w >> 1, b = w & 1;
  vbf16x8 af[2][4];
  #pragma unroll
  for (int ar = 0; ar < 2; ++ar) {
    const u16* rp = xbf + (size_t)(rowbase + (a * 2 + ar) * 16 + lr) * 128;
    #pragma unroll
    for (int ks = 0; ks < 4; ++ks) af[ar][ks] = *(const vbf16x8*)(rp + ks * 32 + lg * 8);
  }
  vf32x4 z = {0.f, 0.f, 0.f, 0.f};
  vf32x4 acc[2][2] = {{z, z}, {z, z}};
  #pragma unroll
  for (int ks = 0; ks < 4; ++ks) {
    vbf16x8 bf[2];
    #pragma unroll
    for (int cbl = 0; cbl < 2; ++cbl) {
      int gcol = cb * 64 + (b * 2 + cbl) * 16 + lr;
      bf[cbl] = *(const vbf16x8*)(wcatT + (size_t)gcol * 128 + ks * 32 + lg * 8);
    }
    #pragma unroll
    for (int ar = 0; ar < 2; ++ar)
      #pragma unroll
      for (int cbl = 0; cbl < 2; ++cbl)
        acc[ar][cbl] = MFMA16(af[ar][ks], bf[cbl], acc[ar][cbl]);
  }
  #pragma unroll
  for (int ar = 0; ar < 2; ++ar)
    #pragma unroll
    for (int cbl = 0; cbl < 2; ++cbl) {
      int gcol = cb * 64 + (b * 2 + cbl) * 16 + lr;
      #pragma unroll
      for (int r = 0; r < 4; ++r) {
        int grow = rowbase + (a * 2 + ar) * 16 + lg * 4 + r;
        float vv = acc[ar][cbl][r];
        if (gcol < 128)      U[(size_t)grow * 128 + gcol] = vv;
        else if (gcol < 256) T[(size_t)grow * 128 + (gcol - 128)] = vv;
        else                 V[(size_t)grow * 128 + (gcol - 256)] = vv;
      }
    }
}

// ---------------- fused: softmax, G = sum_e s_e*relu(T_i+U_j+b1), h_agg, update MLP ----------------
__global__ __launch_bounds__(256) void k_msg_upd(
    const float* __restrict__ x,
    const float* __restrict__ Uarr, const float* __restrict__ Tarr, const float* __restrict__ Varr,
    const float* __restrict__ topV, const int* __restrict__ topI,
    const float* __restrict__ b1, const float* __restrict__ b2,
    const float* __restrict__ ub1, const float* __restrict__ ub2,
    const u16* __restrict__ w2T, const u16* __restrict__ u1bT, const u16* __restrict__ u2T,
    float* __restrict__ out) {
  __shared__ float wsm[32 * 20];
  __shared__ int   ism[32 * 20];
  __shared__ u16   Gbf[32 * 136];
  __shared__ u16   Hbf[32 * 136];
  const int tid = threadIdx.x, lane = tid & 63, w = tid >> 6;
  const int lr = lane & 15, lg = lane >> 4;
  const int base = blockIdx.x * 32;

  if (tid < 32) { // softmax over rescored top-20 sims (order-independent)
    int i = base + tid;
    float vv[20]; float mx = -1e30f;
    #pragma unroll
    for (int e = 0; e < 20; ++e) { vv[e] = topV[(size_t)i * 20 + e]; mx = fmaxf(mx, vv[e]); }
    float s = 0.f;
    #pragma unroll
    for (int e = 0; e < 20; ++e) { vv[e] = __expf(vv[e] - mx); s += vv[e]; }
    float inv = 1.f / s;
    #pragma unroll
    for (int e = 0; e < 20; ++e) {
      wsm[tid * 20 + e] = vv[e] * inv;
      ism[tid * 20 + e] = topI[(size_t)i * 20 + e];
    }
  }
  __syncthreads();

  { // G step: 8 threads per row, 16 channels each
    int r = tid >> 3, q = tid & 7, ch0 = q * 16;
    int i = base + r;
    vf32x4 z = {0.f, 0.f, 0.f, 0.f};
    vf32x4 tr[4], br[4], acc[4];
    #pragma unroll
    for (int c = 0; c < 4; ++c) {
      tr[c] = *(const vf32x4*)&Tarr[(size_t)i * 128 + ch0 + c * 4];
      br[c] = *(const vf32x4*)&b1[ch0 + c * 4];
      acc[c] = z;
    }
    #pragma unroll 1
    for (int e = 0; e < 20; ++e) {
      int j = ism[r * 20 + e]; float s = wsm[r * 20 + e];
      const vf32x4* up = (const vf32x4*)&Uarr[(size_t)j * 128 + ch0];
      #pragma unroll
      for (int c = 0; c < 4; ++c) {
        vf32x4 u = up[c];
        #pragma unroll
        for (int zz = 0; zz < 4; ++zz) {
          float p = tr[c][zz] + u[zz] + br[c][zz];
          acc[c][zz] += s * fmaxf(p, 0.f);
        }
      }
    }
    #pragma unroll
    for (int c = 0; c < 4; ++c)
      #pragma unroll
      for (int zz = 0; zz < 4; ++zz)
        Gbf[r * 136 + ch0 + c * 4 + zz] = f2bf(acc[c][zz]);
  }
  __syncthreads();

  const int rt = w >> 1, cg = w & 1;
  vf32x4 z4 = {0.f, 0.f, 0.f, 0.f};
  { // GEMM1: h_agg = G @ w2 + b2 -> Hbf
    vf32x4 acc[4] = {z4, z4, z4, z4};
    #pragma unroll
    for (int ks = 0; ks < 4; ++ks) {
      vbf16x8 a = *(const vbf16x8*)&Gbf[(rt * 16 + lr) * 136 + ks * 32 + lg * 8];
      #pragma unroll
      for (int c = 0; c < 4; ++c) {
        int col = (cg * 4 + c) * 16 + lr;
        vbf16x8 bb = *(const vbf16x8*)(w2T + (size_t)col * 128 + ks * 32 + lg * 8);
        acc[c] = MFMA16(a, bb, acc[c]);
      }
    }
    #pragma unroll
    for (int c = 0; c < 4; ++c) {
      int col = (cg * 4 + c) * 16 + lr;
      float bias = b2[col];
      #pragma unroll
      for (int r = 0; r < 4; ++r) {
        int row = rt * 16 + lg * 4 + r;
        Hbf[row * 136 + col] = f2bf(acc[c][r] + bias);
      }
    }
  }
  __syncthreads();
  { // GEMM2: pre = h_agg @ uw1[128:] + V_i + ub1, relu -> Gbf (reused as P)
    vf32x4 acc[4] = {z4, z4, z4, z4};
    #pragma unroll
    for (int ks = 0; ks < 4; ++ks) {
      vbf16x8 a = *(const vbf16x8*)&Hbf[(rt * 16 + lr) * 136 + ks * 32 + lg * 8];
      #pragma unroll
      for (int c = 0; c < 4; ++c) {
        int col = (cg * 4 + c) * 16 + lr;
        vbf16x8 bb = *(const vbf16x8*)(u1bT + (size_t)col * 128 + ks * 32 + lg * 8);
        acc[c] = MFMA16(a, bb, acc[c]);
      }
    }
    #pragma unroll
    for (int c = 0; c < 4; ++c) {
      int col = (cg * 4 + c) * 16 + lr;
      float bias = ub1[col];
      #pragma unroll
      for (int r = 0; r < 4; ++r) {
        int row = rt * 16 + lg * 4 + r;
        float vv = acc[c][r] + Varr[(size_t)(base + row) * 128 + col] + bias;
        Gbf[row * 136 + col] = f2bf(fmaxf(vv, 0.f));
      }
    }
  }
  __syncthreads();
  { // GEMM3: out = x + P @ uw2 + ub2
    vf32x4 acc[4] = {z4, z4, z4, z4};
    #pragma unroll
    for (int ks = 0; ks < 4; ++ks) {
      vbf16x8 a = *(const vbf16x8*)&Gbf[(rt * 16 + lr) * 136 + ks * 32 + lg * 8];
      #pragma unroll
      for (int c = 0; c < 4; ++c) {
        int col = (cg * 4 + c) * 16 + lr;
        vbf16x8 bb = *(const vbf16x8*)(u2T + (size_t)col * 128 + ks * 32 + lg * 8);
        acc[c] = MFMA16(a, bb, acc[c]);
      }
    }
    #pragma unroll
    for (int c = 0; c < 4; ++c) {
      int col = (cg * 4 + c) * 16 + lr;
      float bias = ub2[col];
      #pragma unroll
      for (int r = 0; r < 4; ++r) {
        int row = rt * 16 + lg * 4 + r;
        size_t o = (size_t)(base + row) * 128 + col;
        out[o] = x[o] + acc[c][r] + bias;
      }
    }
  }
}

extern "C" void kernel_launch(void* const* d_in, const int* in_sizes, int n_in,
                              void* d_out, int out_size, void* d_ws, size_t ws_size,
                              hipStream_t stream) {
  (void)in_sizes; (void)n_in; (void)out_size; (void)ws_size;
  const float* x   = (const float*)d_in[0];
  const float* w1  = (const float*)d_in[1];
  const float* b1  = (const float*)d_in[2];
  const float* w2  = (const float*)d_in[3];
  const float* b2  = (const float*)d_in[4];
  const float* uw1 = (const float*)d_in[5];
  const float* ub1 = (const float*)d_in[6];
  const float* uw2 = (const float*)d_in[7];
  const float* ub2 = (const float*)d_in[8];
  float* out = (float*)d_out;
  char* ws = (char*)d_ws;

  // Live ranges: sampV [17M,49M) dies after k_theta; Uarr/Tarr/Varr (written by k_pre,
  // which launches after k_theta) overlay it. High-water ~60.3 MB <= 71 MB proven.
  u16*      xnt   = (u16*)(ws + 0);                         // 4 MB (granule-tiled xn)
  u16*      xbf   = (u16*)(ws + (4u << 20));                // 4 MB
  float*    xnf   = (float*)(ws + (8u << 20));              // 8 MB
  u16*      wcatT = (u16*)(ws + (16u << 20));               // 96 KB
  u16*      w2T   = (u16*)(ws + (16u << 20) + 131072);      // 32 KB
  u16*      u1bT  = (u16*)(ws + (16u << 20) + 163840);      // 32 KB
  u16*      u2T   = (u16*)(ws + (16u << 20) + 196608);      // 32 KB
  int*      cnt   = (int*)(ws + (16u << 20) + 262144);      // 64 KB
  float*    thbuf = (float*)(ws + (16u << 20) + 327680);    // 64 KB
  float*    sampV = (float*)(ws + (17u << 20));             // 32 MB (transient)
  float*    Uarr  = (float*)(ws + (17u << 20));             // 8 MB (overlays dead sampV)
  float*    Tarr  = (float*)(ws + (25u << 20));             // 8 MB
  float*    Varr  = (float*)(ws + (33u << 20));             // 8 MB
  int*      candI = (int*)(ws + (49u << 20));               // 8 MB
  float*    topV  = (float*)(ws + (57u << 20));             // 1.31 MB
  int*      topI  = (int*)(ws + (59u << 20));               // 1.31 MB

  hipLaunchKernelGGL(k_prep_w, dim3(384), dim3(256), 0, stream,
                     w1, w2, uw1, uw2, wcatT, w2T, u1bT, u2T);
  hipLaunchKernelGGL(k_norm, dim3(4096), dim3(256), 0, stream, x, xnf, xnt, xbf, cnt);
  hipLaunchKernelGGL(k_sim1, dim3(2048), dim3(256), 0, stream, xnt, sampV);
  hipLaunchKernelGGL(k_theta, dim3(4096), dim3(256), 0, stream, sampV, thbuf);
  hipLaunchKernelGGL(k_sim2, dim3(2048), dim3(256), 0, stream, xnt, thbuf, candI, cnt);
  hipLaunchKernelGGL(k_select, dim3(4096), dim3(256), 0, stream, xnf, candI, cnt, topV, topI);
  hipLaunchKernelGGL(k_pre, dim3(256, 6), dim3(256), 0, stream, xbf, wcatT, Uarr, Tarr, Varr);
  hipLaunchKernelGGL(k_msg_upd, dim3(512), dim3(256), 0, stream,
                     x, Uarr, Tarr, Varr, topV, topI, b1, b2, ub1, ub2, w2T, u1bT, u2T, out);
}

// Round 7
// 299.733 us; speedup vs baseline: 3.2578x; 1.0452x over previous
//
#include <hip/hip_runtime.h>

typedef unsigned short u16;
typedef unsigned int u32;
typedef short vbf16x8 __attribute__((ext_vector_type(8)));   // 8 bf16 as shorts (4 VGPR)
typedef float vf32x4 __attribute__((ext_vector_type(4)));
typedef int vi32x4 __attribute__((ext_vector_type(4)));

#define MFMA16(a,b,c) __builtin_amdgcn_mfma_f32_16x16x32_bf16((a),(b),(c),0,0,0)

__device__ __forceinline__ u16 f2bf(float f) {
  union { float f; unsigned u; } c; c.f = f;
  unsigned r = c.u + 0x7fffu + ((c.u >> 16) & 1u);
  return (u16)(r >> 16);
}
__device__ __forceinline__ u32 umx(u32 a, u32 b) { return a > b ? a : b; }
__device__ __forceinline__ u32 umn(u32 a, u32 b) { return a < b ? a : b; }

// ---------------- prep: weight transposes (bf16) ----------------
__global__ __launch_bounds__(256) void k_prep_w(
    const float* __restrict__ w1, const float* __restrict__ w2,
    const float* __restrict__ u1, const float* __restrict__ u2,
    u16* __restrict__ wcatT, u16* __restrict__ w2T,
    u16* __restrict__ u1bT, u16* __restrict__ u2T) {
  int id = blockIdx.x * 256 + threadIdx.x;
  if (id < 49152) {
    int n = id >> 7, k = id & 127;
    float v;
    if (n < 128) v = w1[(128 + k) * 128 + n];
    else if (n < 256) v = w1[k * 128 + (n - 128)];
    else v = u1[k * 128 + (n - 256)];
    wcatT[id] = f2bf(v);
  } else {
    int id2 = id - 49152;
    int m = id2 >> 14, r = id2 & 16383;
    int n = r >> 7, k = r & 127;
    if (m == 0) w2T[r] = f2bf(w2[k * 128 + n]);
    else if (m == 1) u1bT[r] = f2bf(u1[(128 + k) * 128 + n]);
    else u2T[r] = f2bf(u2[k * 128 + n]);
  }
}

// ---------------- norms: xnf (f32), xbf (raw bf16), xnt (normalized bf16, MFMA-granule-tiled) --------
// xnt layout: granule (row j, ks, lg) = bf16 elems [ks*32+lg*8 .. +8) of row j stored at
// u16 offset (j>>4)*2048 + ks*512 + lg*128 + (j&15)*8. Serves A- and B-fragments directly.
__global__ __launch_bounds__(256) void k_norm(
    const float* __restrict__ x, float* __restrict__ xnf,
    u16* __restrict__ xnt, u16* __restrict__ xbf) {
  __shared__ u16 buf[4][128];
  int tid = threadIdx.x;
  int lane = tid & 63, w = tid >> 6;
  int row = blockIdx.x * 4 + w;
  size_t b = (size_t)row * 128;
  float v0 = x[b + lane], v1 = x[b + 64 + lane];
  float ss = v0 * v0 + v1 * v1;
  #pragma unroll
  for (int m = 32; m > 0; m >>= 1) ss += __shfl_xor(ss, m);
  float d = fmaxf(sqrtf(ss), 1e-8f);
  float n0 = v0 / d, n1 = v1 / d;
  xnf[b + lane] = n0; xnf[b + 64 + lane] = n1;
  xbf[b + lane] = f2bf(v0); xbf[b + 64 + lane] = f2bf(v1);
  buf[w][lane] = f2bf(n0); buf[w][64 + lane] = f2bf(n1);
  __syncthreads();
  if (tid < 64) {
    int r = tid >> 4, g = tid & 15;
    int grow = blockIdx.x * 4 + r;
    vi32x4 d4 = *(const vi32x4*)&buf[r][g * 8];
    *(vi32x4*)&xnt[(size_t)(grow >> 4) * 2048 + (g >> 2) * 512 + (g & 3) * 128 + (grow & 15) * 8] = d4;
  }
}

// ---------------- single sim pass: per-(row,seg-stream) top-3 PACKED KEYS --------------------------
// key = (f32bits(sim + 2.0) & 0xFFFFC000) | col. Monotone in (quantized sim, col); unique per col.
// Block: 256 rows (4 waves x 64 rows) x one 1024-col segment (64 col-tiles). Grid 1024.
// R=64 rows/wave -> 4 B-bytes per sim value through L1 (the round-6 bottleneck, halved).
__global__ __launch_bounds__(256, 2) void k_sim1(
    const u16* __restrict__ xnt, u32* __restrict__ sampK) {
  const int tid = threadIdx.x, lane = tid & 63, w = tid >> 6;
  const int lr = lane & 15, lg = lane >> 4;
  const int seg = blockIdx.x & 15, rbk = blockIdx.x >> 4;
  const int rowbase = rbk * 256 + w * 64;

  vbf16x8 af[4][4];
  #pragma unroll
  for (int a = 0; a < 4; ++a) {
    const u16* tp = xnt + (size_t)((rowbase >> 4) + a) * 2048;
    #pragma unroll
    for (int ks = 0; ks < 4; ++ks)
      af[a][ks] = *(const vbf16x8*)(tp + ks * 512 + lg * 128 + lr * 8);
  }

  u32 k1[4][4], k2[4][4], k3[4][4];
  #pragma unroll
  for (int a = 0; a < 4; ++a)
    #pragma unroll
    for (int r = 0; r < 4; ++r) { k1[a][r] = 0u; k2[a][r] = 0u; k3[a][r] = 0u; }

  const u16* segp = xnt + (size_t)(seg * 64) * 2048;
  vbf16x8 bc[4], bn[4];
  #pragma unroll
  for (int ks = 0; ks < 4; ++ks) bc[ks] = *(const vbf16x8*)(segp + ks * 512 + lane * 8);

  // 5-op top-3 insert on keys: t=min(k1,kv); k1=max(k1,kv); t2=min(k2,t); k2=max(k2,t); k3=max(k3,t2)
#define S1STEP(B, CKEY) { \
  _Pragma("unroll") \
  for (int a = 0; a < 4; ++a) { \
    vf32x4 acc = {0.f, 0.f, 0.f, 0.f}; \
    _Pragma("unroll") \
    for (int ks = 0; ks < 4; ++ks) acc = MFMA16(af[a][ks], (B)[ks], acc); \
    _Pragma("unroll") \
    for (int r = 0; r < 4; ++r) { \
      union { float f; u32 u; } cv; cv.f = acc[r] + 2.0f; \
      u32 kv = (cv.u & 0xFFFFC000u) | (CKEY); \
      u32 t = umn(k1[a][r], kv); \
      k1[a][r] = umx(k1[a][r], kv); \
      u32 t2 = umn(k2[a][r], t); \
      k2[a][r] = umx(k2[a][r], t); \
      k3[a][r] = umx(k3[a][r], t2); \
    } } }

  #pragma unroll 1
  for (int ti = 0; ti < 32; ++ti) {
    { const u16* tp1 = segp + (size_t)(2 * ti + 1) * 2048;
      #pragma unroll
      for (int ks = 0; ks < 4; ++ks) bn[ks] = *(const vbf16x8*)(tp1 + ks * 512 + lane * 8); }
    u32 ck0 = (u32)(seg * 1024 + (2 * ti) * 16 + lr);
    S1STEP(bc, ck0);
    { int nt = (ti < 31) ? (2 * ti + 2) : 63;
      const u16* tp2 = segp + (size_t)nt * 2048;
      #pragma unroll
      for (int ks = 0; ks < 4; ++ks) bc[ks] = *(const vbf16x8*)(tp2 + ks * 512 + lane * 8); }
    u32 ck1 = (u32)(seg * 1024 + (2 * ti + 1) * 16 + lr);
    S1STEP(bn, ck1);
  }

  // dump 48 keys per (row, seg): sampK[row*768 + seg*48 + slot*16 + lr]
  #pragma unroll
  for (int a = 0; a < 4; ++a)
    #pragma unroll
    for (int r = 0; r < 4; ++r) {
      int row = rowbase + a * 16 + lg * 4 + r;
      u32* dp = sampK + (size_t)row * 768 + seg * 48;
      dp[lr] = k1[a][r]; dp[16 + lr] = k2[a][r]; dp[32 + lr] = k3[a][r];
    }
}

// ---------------- candidates: theta = 28th key; emit samples >= theta; expand flagged streams ------
// A stream (seg,lr) can hide values >= theta only if its 3rd-best >= theta (then all 64 cols
// appended; E[#flagged] ~ 0.05/row). Candidate set superset of key-top-28 -> fp32-top-20 safe.
// candI overlays the row's own (already-consumed) sampK storage in-place.
__global__ __launch_bounds__(256) void k_cand(
    const u32* __restrict__ sampK, int* __restrict__ candI, int* __restrict__ cnt) {
  __shared__ u32 keys[4][768];
  const int lane = threadIdx.x & 63, w = threadIdx.x >> 6;
  const int row = blockIdx.x * 4 + w;
  const u32* sp = sampK + (size_t)row * 768;
  u32 kq[12];
  #pragma unroll
  for (int q = 0; q < 12; ++q) { kq[q] = sp[q * 64 + lane]; keys[w][q * 64 + lane] = kq[q]; }
  __syncthreads();

  // theta = 28th-largest of 768 keys (max-extract; keys unique since low 14 bits = col)
  u32 tmp[12];
  #pragma unroll
  for (int q = 0; q < 12; ++q) tmp[q] = kq[q];
  u32 g = 0u;
  #pragma unroll 1
  for (int t = 0; t < 28; ++t) {
    u32 loc = tmp[0];
    #pragma unroll
    for (int q = 1; q < 12; ++q) loc = umx(loc, tmp[q]);
    g = loc;
    #pragma unroll
    for (int mm = 1; mm < 64; mm <<= 1) g = umx(g, (u32)__shfl_xor((int)g, mm));
    #pragma unroll
    for (int q = 0; q < 12; ++q) tmp[q] = (tmp[q] == g) ? 0u : tmp[q];
  }
  const u32 th = g;

  int cbase = 0;
  // samples >= theta from UNFLAGGED streams (flagged streams covered by expansion; avoids dups)
  #pragma unroll
  for (int q = 0; q < 12; ++q) {
    int f = q * 64 + lane;
    int i16 = f >> 4;                     // 0..47
    int sg = (i16 * 171) >> 9;            // i16 / 3 (exact for 0..47)
    int lrr = f & 15;
    u32 key3 = keys[w][sg * 48 + 32 + lrr];
    bool e = (kq[q] >= th) && (key3 < th);
    unsigned long long ball = __ballot(e);
    if (e) {
      int pos = __popcll(ball & ((1ull << lane) - 1ull));
      candI[(size_t)row * 768 + cbase + pos] = (int)(kq[q] & 0x3FFFu);
    }
    cbase += __popcll(ball);
  }
  // expansion: flagged streams -> all 64 member cols (col = sg*1024 + k*16 + lr)
  #pragma unroll 1
  for (int t = 0; t < 4; ++t) {
    int strm = t * 64 + lane;
    int sg = strm >> 4, lrr = strm & 15;
    bool fl = keys[w][sg * 48 + 32 + lrr] >= th;
    unsigned long long mask = __ballot(fl);
    while (mask != 0ull && cbase + 64 <= 768) {
      int b = __ffsll((long long)mask) - 1;
      mask &= mask - 1ull;
      int strmb = t * 64 + b;
      int sgb = strmb >> 4, lrb = strmb & 15;
      candI[(size_t)row * 768 + cbase + lane] = sgb * 1024 + lane * 16 + lrb;
      cbase += 64;
    }
  }
  if (lane == 0) cnt[row] = cbase;
}

// ---------------- select: rescore ALL candidates (fp32, half-wave each), rank-count top-20 ---------
__global__ __launch_bounds__(256) void k_select(
    const float* __restrict__ xnf,
    const int* __restrict__ candI, const int* __restrict__ cnt,
    float* __restrict__ topV, int* __restrict__ topI) {
  __shared__ float svals[4][384];
  __shared__ int   sidx[4][384];
  const int tid = threadIdx.x, lane = tid & 63, w = tid >> 6;
  const int i = blockIdx.x * 4 + w;
  const int q = lane >> 5, ll = lane & 31;
  int c = cnt[i]; if (c > 384) c = 384;
  const int* ci = candI + (size_t)i * 768;
  vf32x4 xi = *(const vf32x4*)&xnf[(size_t)i * 128 + ll * 4];
  // rescore: half-wave (32 lanes) per candidate, two candidates per iteration
  #pragma unroll 1
  for (int sp = 0; sp < c; sp += 2) {
    int s2 = sp + q;
    bool val = s2 < c;
    int j = ci[val ? s2 : sp];
    vf32x4 xj = *(const vf32x4*)&xnf[(size_t)j * 128 + ll * 4];
    float p = xi[0] * xj[0] + xi[1] * xj[1] + xi[2] * xj[2] + xi[3] * xj[3];
    #pragma unroll
    for (int m = 1; m < 32; m <<= 1) p += __shfl_xor(p, m);
    if (ll == 0 && val) { svals[w][s2] = p; sidx[w][s2] = j; }
  }
  __syncthreads();
  // rank by pairwise counting; winners = rank < 20 under (value desc, index asc) total order
  float v[6]; int ix[6];
  #pragma unroll
  for (int h = 0; h < 6; ++h) {
    int s = h * 64 + lane;
    bool ok = s < c;
    v[h] = ok ? svals[w][s] : -1e30f;
    ix[h] = ok ? sidx[w][s] : 0x7fffffff;
  }
  int rk[6] = {0, 0, 0, 0, 0, 0};
  #pragma unroll 1
  for (int s = 0; s < c; ++s) {
    float vs = svals[w][s]; int is = sidx[w][s];
    #pragma unroll
    for (int h = 0; h < 6; ++h)
      rk[h] += (vs > v[h] || (vs == v[h] && is < ix[h])) ? 1 : 0;
  }
  int base = 0;
  #pragma unroll
  for (int h = 0; h < 6; ++h) {
    bool win = (h * 64 + lane < c) && (rk[h] < 20);
    unsigned long long bl = __ballot(win);
    if (win) {
      int pos = base + __popcll(bl & ((1ull << lane) - 1ull));
      topV[(size_t)i * 20 + pos] = v[h]; topI[(size_t)i * 20 + pos] = ix[h];
    }
    base += __popcll(bl);
  }
}

// ---------------- precompute U = x@w1[128:], T = x@w1[:128], V = x@uw1[:128] ----------------
__global__ __launch_bounds__(256) void k_pre(
    const u16* __restrict__ xbf, const u16* __restrict__ wcatT,
    float* __restrict__ U, float* __restrict__ T, float* __restrict__ V) {
  const int tid = threadIdx.x, lane = tid & 63, w = tid >> 6;
  const int lr = lane & 15, lg = lane >> 4;
  const int rowbase = blockIdx.x * 64, cb = blockIdx.y;
  const int a = w >> 1, b = w & 1;
  vbf16x8 af[2][4];
  #pragma unroll
  for (int ar = 0; ar < 2; ++ar) {
    const u16* rp = xbf + (size_t)(rowbase + (a * 2 + ar) * 16 + lr) * 128;
    #pragma unroll
    for (int ks = 0; ks < 4; ++ks) af[ar][ks] = *(const vbf16x8*)(rp + ks * 32 + lg * 8);
  }
  vf32x4 z = {0.f, 0.f, 0.f, 0.f};
  vf32x4 acc[2][2] = {{z, z}, {z, z}};
  #pragma unroll
  for (int ks = 0; ks < 4; ++ks) {
    vbf16x8 bf[2];
    #pragma unroll
    for (int cbl = 0; cbl < 2; ++cbl) {
      int gcol = cb * 64 + (b * 2 + cbl) * 16 + lr;
      bf[cbl] = *(const vbf16x8*)(wcatT + (size_t)gcol * 128 + ks * 32 + lg * 8);
    }
    #pragma unroll
    for (int ar = 0; ar < 2; ++ar)
      #pragma unroll
      for (int cbl = 0; cbl < 2; ++cbl)
        acc[ar][cbl] = MFMA16(af[ar][ks], bf[cbl], acc[ar][cbl]);
  }
  #pragma unroll
  for (int ar = 0; ar < 2; ++ar)
    #pragma unroll
    for (int cbl = 0; cbl < 2; ++cbl) {
      int gcol = cb * 64 + (b * 2 + cbl) * 16 + lr;
      #pragma unroll
      for (int r = 0; r < 4; ++r) {
        int grow = rowbase + (a * 2 + ar) * 16 + lg * 4 + r;
        float vv = acc[ar][cbl][r];
        if (gcol < 128)      U[(size_t)grow * 128 + gcol] = vv;
        else if (gcol < 256) T[(size_t)grow * 128 + (gcol - 128)] = vv;
        else                 V[(size_t)grow * 128 + (gcol - 256)] = vv;
      }
    }
}

// ---------------- fused: softmax, G = sum_e s_e*relu(T_i+U_j+b1), h_agg, update MLP ----------------
__global__ __launch_bounds__(256) void k_msg_upd(
    const float* __restrict__ x,
    const float* __restrict__ Uarr, const float* __restrict__ Tarr, const float* __restrict__ Varr,
    const float* __restrict__ topV, const int* __restrict__ topI,
    const float* __restrict__ b1, const float* __restrict__ b2,
    const float* __restrict__ ub1, const float* __restrict__ ub2,
    const u16* __restrict__ w2T, const u16* __restrict__ u1bT, const u16* __restrict__ u2T,
    float* __restrict__ out) {
  __shared__ float wsm[32 * 20];
  __shared__ int   ism[32 * 20];
  __shared__ u16   Gbf[32 * 136];
  __shared__ u16   Hbf[32 * 136];
  const int tid = threadIdx.x, lane = tid & 63, w = tid >> 6;
  const int lr = lane & 15, lg = lane >> 4;
  const int base = blockIdx.x * 32;

  if (tid < 32) { // softmax over rescored top-20 sims (order-independent)
    int i = base + tid;
    float vv[20]; float mx = -1e30f;
    #pragma unroll
    for (int e = 0; e < 20; ++e) { vv[e] = topV[(size_t)i * 20 + e]; mx = fmaxf(mx, vv[e]); }
    float s = 0.f;
    #pragma unroll
    for (int e = 0; e < 20; ++e) { vv[e] = __expf(vv[e] - mx); s += vv[e]; }
    float inv = 1.f / s;
    #pragma unroll
    for (int e = 0; e < 20; ++e) {
      wsm[tid * 20 + e] = vv[e] * inv;
      ism[tid * 20 + e] = topI[(size_t)i * 20 + e];
    }
  }
  __syncthreads();

  { // G step: 8 threads per row, 16 channels each
    int r = tid >> 3, q = tid & 7, ch0 = q * 16;
    int i = base + r;
    vf32x4 z = {0.f, 0.f, 0.f, 0.f};
    vf32x4 tr[4], br[4], acc[4];
    #pragma unroll
    for (int c = 0; c < 4; ++c) {
      tr[c] = *(const vf32x4*)&Tarr[(size_t)i * 128 + ch0 + c * 4];
      br[c] = *(const vf32x4*)&b1[ch0 + c * 4];
      acc[c] = z;
    }
    #pragma unroll 1
    for (int e = 0; e < 20; ++e) {
      int j = ism[r * 20 + e]; float s = wsm[r * 20 + e];
      const vf32x4* up = (const vf32x4*)&Uarr[(size_t)j * 128 + ch0];
      #pragma unroll
      for (int c = 0; c < 4; ++c) {
        vf32x4 u = up[c];
        #pragma unroll
        for (int zz = 0; zz < 4; ++zz) {
          float p = tr[c][zz] + u[zz] + br[c][zz];
          acc[c][zz] += s * fmaxf(p, 0.f);
        }
      }
    }
    #pragma unroll
    for (int c = 0; c < 4; ++c)
      #pragma unroll
      for (int zz = 0; zz < 4; ++zz)
        Gbf[r * 136 + ch0 + c * 4 + zz] = f2bf(acc[c][zz]);
  }
  __syncthreads();

  const int rt = w >> 1, cg = w & 1;
  vf32x4 z4 = {0.f, 0.f, 0.f, 0.f};
  { // GEMM1: h_agg = G @ w2 + b2 -> Hbf
    vf32x4 acc[4] = {z4, z4, z4, z4};
    #pragma unroll
    for (int ks = 0; ks < 4; ++ks) {
      vbf16x8 a = *(const vbf16x8*)&Gbf[(rt * 16 + lr) * 136 + ks * 32 + lg * 8];
      #pragma unroll
      for (int c = 0; c < 4; ++c) {
        int col = (cg * 4 + c) * 16 + lr;
        vbf16x8 bb = *(const vbf16x8*)(w2T + (size_t)col * 128 + ks * 32 + lg * 8);
        acc[c] = MFMA16(a, bb, acc[c]);
      }
    }
    #pragma unroll
    for (int c = 0; c < 4; ++c) {
      int col = (cg * 4 + c) * 16 + lr;
      float bias = b2[col];
      #pragma unroll
      for (int r = 0; r < 4; ++r) {
        int row = rt * 16 + lg * 4 + r;
        Hbf[row * 136 + col] = f2bf(acc[c][r] + bias);
      }
    }
  }
  __syncthreads();
  { // GEMM2: pre = h_agg @ uw1[128:] + V_i + ub1, relu -> Gbf (reused as P)
    vf32x4 acc[4] = {z4, z4, z4, z4};
    #pragma unroll
    for (int ks = 0; ks < 4; ++ks) {
      vbf16x8 a = *(const vbf16x8*)&Hbf[(rt * 16 + lr) * 136 + ks * 32 + lg * 8];
      #pragma unroll
      for (int c = 0; c < 4; ++c) {
        int col = (cg * 4 + c) * 16 + lr;
        vbf16x8 bb = *(const vbf16x8*)(u1bT + (size_t)col * 128 + ks * 32 + lg * 8);
        acc[c] = MFMA16(a, bb, acc[c]);
      }
    }
    #pragma unroll
    for (int c = 0; c < 4; ++c) {
      int col = (cg * 4 + c) * 16 + lr;
      float bias = ub1[col];
      #pragma unroll
      for (int r = 0; r < 4; ++r) {
        int row = rt * 16 + lg * 4 + r;
        float vv = acc[c][r] + Varr[(size_t)(base + row) * 128 + col] + bias;
        Gbf[row * 136 + col] = f2bf(fmaxf(vv, 0.f));
      }
    }
  }
  __syncthreads();
  { // GEMM3: out = x + P @ uw2 + ub2
    vf32x4 acc[4] = {z4, z4, z4, z4};
    #pragma unroll
    for (int ks = 0; ks < 4; ++ks) {
      vbf16x8 a = *(const vbf16x8*)&Gbf[(rt * 16 + lr) * 136 + ks * 32 + lg * 8];
      #pragma unroll
      for (int c = 0; c < 4; ++c) {
        int col = (cg * 4 + c) * 16 + lr;
        vbf16x8 bb = *(const vbf16x8*)(u2T + (size_t)col * 128 + ks * 32 + lg * 8);
        acc[c] = MFMA16(a, bb, acc[c]);
      }
    }
    #pragma unroll
    for (int c = 0; c < 4; ++c) {
      int col = (cg * 4 + c) * 16 + lr;
      float bias = ub2[col];
      #pragma unroll
      for (int r = 0; r < 4; ++r) {
        int row = rt * 16 + lg * 4 + r;
        size_t o = (size_t)(base + row) * 128 + col;
        out[o] = x[o] + acc[c][r] + bias;
      }
    }
  }
}

extern "C" void kernel_launch(void* const* d_in, const int* in_sizes, int n_in,
                              void* d_out, int out_size, void* d_ws, size_t ws_size,
                              hipStream_t stream) {
  (void)in_sizes; (void)n_in; (void)out_size; (void)ws_size;
  const float* x   = (const float*)d_in[0];
  const float* w1  = (const float*)d_in[1];
  const float* b1  = (const float*)d_in[2];
  const float* w2  = (const float*)d_in[3];
  const float* b2  = (const float*)d_in[4];
  const float* uw1 = (const float*)d_in[5];
  const float* ub1 = (const float*)d_in[6];
  const float* uw2 = (const float*)d_in[7];
  const float* ub2 = (const float*)d_in[8];
  float* out = (float*)d_out;
  char* ws = (char*)d_ws;

  // Live ranges: sampK [17M,65M) written by k_sim1, consumed by k_cand which overwrites each
  // row's storage in-place with candI (stride 768, first <=768 ints); candI read by k_select.
  // U/T/V @ [17M,41M) written by k_pre AFTER k_select -> overlay OK. High-water ~68 MB.
  u16*   xnt   = (u16*)(ws + 0);                         // 4 MB (granule-tiled xn)
  u16*   xbf   = (u16*)(ws + (4u << 20));                // 4 MB
  float* xnf   = (float*)(ws + (8u << 20));              // 8 MB
  u16*   wcatT = (u16*)(ws + (16u << 20));               // 96 KB
  u16*   w2T   = (u16*)(ws + (16u << 20) + 131072);      // 32 KB
  u16*   u1bT  = (u16*)(ws + (16u << 20) + 163840);      // 32 KB
  u16*   u2T   = (u16*)(ws + (16u << 20) + 196608);      // 32 KB
  int*   cnt   = (int*)(ws + (16u << 20) + 262144);      // 64 KB
  u32*   sampK = (u32*)(ws + (17u << 20));               // 48 MB (transient)
  int*   candI = (int*)(ws + (17u << 20));               // in-place overlay of sampK
  float* Uarr  = (float*)(ws + (17u << 20));             // 8 MB (after candI dead)
  float* Tarr  = (float*)(ws + (25u << 20));             // 8 MB
  float* Varr  = (float*)(ws + (33u << 20));             // 8 MB
  float* topV  = (float*)(ws + (65u << 20));             // 1.31 MB
  int*   topI  = (int*)(ws + (67u << 20));               // 1.31 MB

  hipLaunchKernelGGL(k_prep_w, dim3(384), dim3(256), 0, stream,
                     w1, w2, uw1, uw2, wcatT, w2T, u1bT, u2T);
  hipLaunchKernelGGL(k_norm, dim3(4096), dim3(256), 0, stream, x, xnf, xnt, xbf);
  hipLaunchKernelGGL(k_sim1, dim3(1024), dim3(256), 0, stream, xnt, sampK);
  hipLaunchKernelGGL(k_cand, dim3(4096), dim3(256), 0, stream, sampK, candI, cnt);
  hipLaunchKernelGGL(k_select, dim3(4096), dim3(256), 0, stream, xnf, candI, cnt, topV, topI);
  hipLaunchKernelGGL(k_pre, dim3(256, 6), dim3(256), 0, stream, xbf, wcatT, Uarr, Tarr, Varr);
  hipLaunchKernelGGL(k_msg_upd, dim3(512), dim3(256), 0, stream,
                     x, Uarr, Tarr, Varr, topV, topI, b1, b2, ub1, ub2, w2T, u1bT, u2T, out);
}